// Round 11
// baseline (399.097 us; speedup 1.0000x reference)
//
#include <hip/hip_runtime.h>

// ---------------------------------------------------------------------------
// Transformer block on MI355X. fp32 I/O (per reference), bf16 MFMA internals,
// fp32 accumulation/residuals.
// R20 == R19 resubmit ("container failed twice" = same infra flake signature
// as R15/R16; audit of gemm_fc2 found no hang/fault path: bounds OK, vmcnt
// ledger exact w/ sched_barrier pinning, barriers uniform, reg-WAR ordered).
// R19: revert R18's wave-split-K (FAILED: FETCH 57->90MB, both K-halves of A
// hot per block -> L2 thrash) back to R17 gemm_bt. FC2 theory from R17
// counters: 64^2 = 1.0 ds_read_b128/MFMA -> LDS-BW-bound (reads 384 + writes
// 128 of 506 cyc/slot). gemm_fc2 takes B OUT of LDS: wT2 row layout IS the
// fragment layout (row = n0+wn+t*16+l16, no swizzle), L2-resident; B double-
// buffered in NAMED register sets bR0/bR1 (2-unrolled kt loop, rule #20),
// prefetched one tile ahead; vmcnt(6) = 2 async16 + 4 B-loads. LDS halves.
// R17 kept: gemm256 register-resident fragments. R15/16: flash tr-read V,
// lsK dbuf, accL K=32 pairs. R14: 8-phase 256^2 FC1. R13: XCD-chunk swizzle,
// fused combine-proj. R11/12: 2-phase dbuf 64^2 GEMMs. R10: kexp in kh,
// cvt_pk, bare exp2. R9: XCD-local flash grid.
// ws layout (56MB min, 72MB preferred):
//   [0,16M)  Opart | big: fc1o [0,32M) after proj
//   [16,24M) kh    | fallback: fc1o [16,32M)
//   [24,32M) (free; was khT)
//   [32,48M) x1    [48,56M) hbuf + lpart during flash
//   [56,64M) wT1 (big), [64,72M) wT2 (big)
// ---------------------------------------------------------------------------

typedef __attribute__((ext_vector_type(8))) short s8v;  // 8 bf16 raw
typedef __attribute__((ext_vector_type(4))) short s4v;  // 4 bf16 raw
typedef __attribute__((ext_vector_type(4))) float f4v;  // mfma accumulator

#define D_MODEL 1024
#define SEQ 2048
#define BATCH 2
#define NH 16
#define DH 64
#define MROWS (BATCH * SEQ)

#define KH_SCALE 0.42466088f
#define KH_ISCALE 2.3548200f

__device__ __forceinline__ float b2f(unsigned short u) {
  union { unsigned int i; float f; } v; v.i = ((unsigned int)u) << 16; return v.f;
}
__device__ __forceinline__ unsigned short f2b(float f) {
  unsigned int i = __builtin_bit_cast(unsigned int, f);
  unsigned int r = (i + 0x7fffu + ((i >> 16) & 1u)) >> 16;  // RNE
  return (unsigned short)r;
}
// async global->LDS, 16B/lane; dest = wave-uniform base + lane*16 (m104/m108)
__device__ __forceinline__ void async16(const void* g, void* l) {
  __builtin_amdgcn_global_load_lds(
      (const __attribute__((address_space(1))) unsigned int*)g,
      (__attribute__((address_space(3))) unsigned int*)l, 16, 0, 0);
}
__device__ __forceinline__ unsigned short cvt_b(float f) { return f2b(f); }
__device__ __forceinline__ unsigned short cvt_b(unsigned short u) { return u; }

__device__ __forceinline__ float xp2(float x) {
#if __has_builtin(__builtin_amdgcn_exp2f)
  return __builtin_amdgcn_exp2f(x);
#else
  return exp2f(x);
#endif
}

// 4x f32 -> packed bf16 s4v via v_cvt_pk_bf16_f32 (RNE, 2 instructions).
__device__ __forceinline__ s4v cvt4(float a, float b, float c, float d) {
  unsigned int lo, hi;
  asm("v_cvt_pk_bf16_f32 %0, %1, %2" : "=v"(lo) : "v"(a), "v"(b));
  asm("v_cvt_pk_bf16_f32 %0, %1, %2" : "=v"(hi) : "v"(c), "v"(d));
  union { unsigned long long u; s4v v; } u;
  u.u = ((unsigned long long)hi << 32) | (unsigned long long)lo;
  return u.v;
}

#if __has_builtin(__builtin_amdgcn_mfma_f32_16x16x16_bf16)
__device__ __forceinline__ f4v mfma16(s4v a, s4v b, f4v c) {
  return __builtin_amdgcn_mfma_f32_16x16x16_bf16(a, b, c, 0, 0, 0);
}
#elif __has_builtin(__builtin_amdgcn_mfma_f32_16x16x16bf16_1k)
__device__ __forceinline__ f4v mfma16(s4v a, s4v b, f4v c) {
  return __builtin_amdgcn_mfma_f32_16x16x16bf16_1k(a, b, c, 0, 0, 0);
}
#else
__device__ __forceinline__ f4v mfma16(s4v a, s4v b, f4v c) {
  s8v aa = {a[0], a[1], a[2], a[3], 0, 0, 0, 0};
  s8v bb = {b[0], b[1], b[2], b[3], 0, 0, 0, 0};
  return __builtin_amdgcn_mfma_f32_16x16x32_bf16(aa, bb, c, 0, 0, 0);
}
#endif

// LDS transpose-read: supply the natural per-lane ds_read_b64 address
// (base + lane*8B); each 16-lane group's 128B region is delivered
// column-major: lane l gets column (l&15) of its 4x16 bf16 tile (m156/m162).
typedef __attribute__((address_space(3))) const unsigned short* lds_cp;
__device__ __forceinline__ s4v tr16(lds_cp p) {
  unsigned long long d;
  asm volatile("ds_read_b64_tr_b16 %0, %1" : "=v"(d) : "v"(p));
  return __builtin_bit_cast(s4v, d);
}

// XCD-chunked logical block id (T1); bijective only when nwg%8==0.
__device__ __forceinline__ int xcd_swz(int bidl, int nwg) {
  return (nwg & 7) ? bidl : ((bidl & 7) * (nwg >> 3) + (bidl >> 3));
}

// ---------------- LayerNorm: fp32 in -> bf16 out, one block per row ---------
__global__ __launch_bounds__(256) void ln_kernel(
    const float* __restrict__ x, const float* __restrict__ g,
    const float* __restrict__ bb, unsigned short* __restrict__ out) {
  int row = blockIdx.x;
  int t = threadIdx.x;
  const float* xr = x + (size_t)row * D_MODEL;
  float v[4];
  float s = 0.f, s2 = 0.f;
#pragma unroll
  for (int i = 0; i < 4; ++i) {
    float f = xr[t + 256 * i];
    v[i] = f; s += f; s2 += f * f;
  }
#pragma unroll
  for (int off = 1; off < 64; off <<= 1) {
    s += __shfl_xor(s, off, 64);
    s2 += __shfl_xor(s2, off, 64);
  }
  __shared__ float red[8];
  if ((t & 63) == 0) { red[t >> 6] = s; red[4 + (t >> 6)] = s2; }
  __syncthreads();
  s = red[0] + red[1] + red[2] + red[3];
  s2 = red[4] + red[5] + red[6] + red[7];
  float mu = s * (1.f / D_MODEL);
  float var = s2 * (1.f / D_MODEL) - mu * mu;
  float rstd = rsqrtf(var + 1e-5f);
#pragma unroll
  for (int i = 0; i < 4; ++i) {
    int c = t + 256 * i;
    float h = (v[i] - mu) * rstd * g[c] + bb[c];
    out[(size_t)row * D_MODEL + c] = f2b(h);
  }
}

// ---------------- batched 64x64 tile transpose -> bf16 ----------------------
template <typename T>
__global__ __launch_bounds__(256) void transpose_b(
    const T* __restrict__ src, unsigned short* __restrict__ dst,
    int srcStride, int dstStride, long long srcBatch, long long dstBatch) {
  __shared__ unsigned short tile[64][65];
  const T* s = src + (size_t)blockIdx.z * srcBatch;
  unsigned short* d = dst + (size_t)blockIdx.z * dstBatch;
  int n0 = blockIdx.x * 64, k0 = blockIdx.y * 64;
  for (int i = threadIdx.x; i < 4096; i += 256) {
    int k = i >> 6, n = i & 63;
    tile[k][n] = cvt_b(s[(size_t)(k0 + k) * srcStride + n0 + n]);
  }
  __syncthreads();
  for (int i = threadIdx.x; i < 4096; i += 256) {
    int n = i >> 6, k = i & 63;
    d[(size_t)(n0 + n) * dstStride + k0 + k] = tile[k][n];
  }
}

// ---------------- GEMM: C[M,N] = A[M,K] @ Bt[N,K]^T + bias (+res)(+relu) ----
// BMxBN tile, BK=64, 4 waves (2x2); 2-phase dbuf, counted vmcnt, raw barrier.
template <int RES, bool RELU, bool KH, int OUTF, int BM, int BN>
__global__ __launch_bounds__(256) void gemm_bt(
    const unsigned short* __restrict__ A, const unsigned short* __restrict__ Bt,
    const float* __restrict__ bias, const float* __restrict__ res,
    void* __restrict__ out, int M, int N, int K) {
  constexpr int MT = BM / 32;
  constexpr int NT = BN / 32;
  __shared__ __align__(16) unsigned short lsA[2][BM * 64];
  __shared__ __align__(16) unsigned short lsB[2][BN * 64];
  int tid = threadIdx.x;
  int lane = tid & 63, w = tid >> 6, quad = lane >> 4, l16 = lane & 15;
  int bidl = blockIdx.y * (int)gridDim.x + blockIdx.x;
  int swz = xcd_swz(bidl, (int)(gridDim.x * gridDim.y));
  int m0 = (swz / (int)gridDim.x) * BM, n0 = (swz % (int)gridDim.x) * BN;
  int wm = (w >> 1) * (BM / 2), wn = (w & 1) * (BN / 2);
  f4v acc[MT][NT] = {};

  auto stage = [&](int bsel, int ktE) {
#pragma unroll
    for (int i = 0; i < MT; ++i) {
      int cb = w * (BM * 2) + i * 64;
      int ci = cb + lane;
      int row = ci >> 3, c = ci & 7;
      int cs = c ^ (row & 7);
      async16(A + (size_t)(m0 + row) * K + ktE + cs * 8, &lsA[bsel][cb * 8]);
    }
#pragma unroll
    for (int i = 0; i < NT; ++i) {
      int cb = w * (BN * 2) + i * 64;
      int ci = cb + lane;
      int row = ci >> 3, c = ci & 7;
      int cs = c ^ (row & 7);
      async16(Bt + (size_t)(n0 + row) * K + ktE + cs * 8, &lsB[bsel][cb * 8]);
    }
  };

  stage(0, 0);
  int nK = K >> 6;
  for (int kt = 0; kt < nK; ++kt) {
    int b = kt & 1;
    if (kt + 1 < nK) {
      stage(b ^ 1, (kt + 1) << 6);
      if constexpr (MT + NT == 4)      asm volatile("s_waitcnt vmcnt(4)" ::: "memory");
      else if constexpr (MT + NT == 6) asm volatile("s_waitcnt vmcnt(6)" ::: "memory");
      else                             asm volatile("s_waitcnt vmcnt(8)" ::: "memory");
    } else {
      asm volatile("s_waitcnt vmcnt(0)" ::: "memory");
    }
    __builtin_amdgcn_sched_barrier(0);
    __builtin_amdgcn_s_barrier();
    __builtin_amdgcn_sched_barrier(0);
#pragma unroll
    for (int s = 0; s < 2; ++s) {
      s8v af[MT], bf[NT];
#pragma unroll
      for (int t = 0; t < MT; ++t) {
        int am = wm + t * 16 + l16;
        int ac = (s * 4 + quad) ^ (am & 7);
        af[t] = *(const s8v*)(&lsA[b][am * 64 + ac * 8]);
      }
#pragma unroll
      for (int t = 0; t < NT; ++t) {
        int bn = wn + t * 16 + l16;
        int bc = (s * 4 + quad) ^ (bn & 7);
        bf[t] = *(const s8v*)(&lsB[b][bn * 64 + bc * 8]);
      }
#pragma unroll
      for (int ti = 0; ti < MT; ++ti)
#pragma unroll
        for (int tj = 0; tj < NT; ++tj)
          acc[ti][tj] = __builtin_amdgcn_mfma_f32_16x16x32_bf16(
              af[ti], bf[tj], acc[ti][tj], 0, 0, 0);
    }
    asm volatile("s_waitcnt lgkmcnt(0)" ::: "memory");
    __builtin_amdgcn_sched_barrier(0);
    __builtin_amdgcn_s_barrier();
    __builtin_amdgcn_sched_barrier(0);
  }
#pragma unroll
  for (int tj = 0; tj < NT; ++tj) {
    int col = n0 + wn + tj * 16 + l16;
    float bv = bias[col];
#pragma unroll
    for (int ti = 0; ti < MT; ++ti) {
#pragma unroll
      for (int r = 0; r < 4; ++r) {
        int rowg = m0 + wm + ti * 16 + quad * 4 + r;
        float vv = acc[ti][tj][r] + bv;
        if (KH) vv *= KH_SCALE;
        if (RES == 2) vv += res[(size_t)rowg * N + col];
        if (RELU) vv = fmaxf(vv, 0.f);
        size_t oidx;
        if (KH) {
          int b2 = rowg >> 11, l = rowg & 2047, h = col >> 6, d = col & 63;
          oidx = (((size_t)(b2 * NH + h)) * SEQ + l) * DH + d;
        } else {
          oidx = (size_t)rowg * N + col;
        }
        if (OUTF == 0) ((unsigned short*)out)[oidx] = f2b(vv);
        else           ((float*)out)[oidx] = vv;
      }
    }
  }
}

// ---------------- FC2 GEMM: 64x64 tile, B in registers (no lsB) -------------
// R19: out = A @ Bt^T + bias + res (fp32). A staged via global_load_lds dbuf
// (16KB LDS); B fragments loaded straight from global per lane (wT2 row
// layout = fragment layout, no swizzle), double-buffered in NAMED register
// sets bR0/bR1 with a 2-unrolled kt loop (rule #20). vmcnt(6) = this step's
// 2 async16 + 4 B-loads in flight; waits previous step's 6. Halves LDS
// traffic vs gemm_bt (1.0 -> 0.5 ds_read_b128/MFMA) at same occupancy.
__global__ __launch_bounds__(256) void gemm_fc2(
    const unsigned short* __restrict__ A, const unsigned short* __restrict__ Bt,
    const float* __restrict__ bias, const float* __restrict__ res,
    float* __restrict__ out, int M, int N, int K) {
  __shared__ __align__(16) unsigned short lsA[2][64 * 64];  // 16 KB
  int tid = threadIdx.x;
  int lane = tid & 63, w = tid >> 6, quad = lane >> 4, l16 = lane & 15;
  int bidl = blockIdx.y * (int)gridDim.x + blockIdx.x;
  int swz = xcd_swz(bidl, (int)(gridDim.x * gridDim.y));
  int m0 = (swz / (int)gridDim.x) * 64, n0 = (swz % (int)gridDim.x) * 64;
  int wm = (w >> 1) * 32, wn = (w & 1) * 32;
  f4v acc[2][2] = {};

  // fixed per-lane B fragment pointers [t][s]
  const unsigned short* bp[2][2];
#pragma unroll
  for (int t = 0; t < 2; ++t)
#pragma unroll
    for (int s = 0; s < 2; ++s)
      bp[t][s] = Bt + (size_t)(n0 + wn + t * 16 + l16) * K + (s * 4 + quad) * 8;

  auto stageA = [&](int bsel, int ktE) {
#pragma unroll
    for (int i = 0; i < 2; ++i) {
      int cb = w * 128 + i * 64;
      int ci = cb + lane;
      int row = ci >> 3, c = ci & 7;
      int cs = c ^ (row & 7);
      async16(A + (size_t)(m0 + row) * K + ktE + cs * 8, &lsA[bsel][cb * 8]);
    }
  };
  auto loadB = [&](s8v (&bR)[2][2], int kt) {
#pragma unroll
    for (int t = 0; t < 2; ++t)
#pragma unroll
      for (int s = 0; s < 2; ++s)
        bR[t][s] = *(const s8v*)(bp[t][s] + (size_t)kt * 64);
  };
  auto compute = [&](int bsel, const s8v (&bR)[2][2]) {
#pragma unroll
    for (int s = 0; s < 2; ++s) {
      s8v af[2];
#pragma unroll
      for (int t = 0; t < 2; ++t) {
        int am = wm + t * 16 + l16;
        int ac = (s * 4 + quad) ^ (am & 7);
        af[t] = *(const s8v*)(&lsA[bsel][am * 64 + ac * 8]);
      }
#pragma unroll
      for (int ti = 0; ti < 2; ++ti)
#pragma unroll
        for (int tj = 0; tj < 2; ++tj)
          acc[ti][tj] = __builtin_amdgcn_mfma_f32_16x16x32_bf16(
              af[ti], bR[tj][s], acc[ti][tj], 0, 0, 0);
    }
  };

  s8v bR0[2][2], bR1[2][2];
  stageA(0, 0);
  loadB(bR0, 0);
  int nK = K >> 6;  // even (FC2: 64)
  for (int kt = 0; kt < nK; kt += 2) {
    // even step: compute buf0/bR0, prefetch kt+1 -> buf1/bR1
    if (kt + 1 < nK) {
      stageA(1, (kt + 1) << 6);
      loadB(bR1, kt + 1);
      __builtin_amdgcn_sched_barrier(0);
      asm volatile("s_waitcnt vmcnt(6)" ::: "memory");
    } else {
      __builtin_amdgcn_sched_barrier(0);
      asm volatile("s_waitcnt vmcnt(0)" ::: "memory");
    }
    __builtin_amdgcn_sched_barrier(0);
    __builtin_amdgcn_s_barrier();
    __builtin_amdgcn_sched_barrier(0);
    compute(0, bR0);
    asm volatile("s_waitcnt lgkmcnt(0)" ::: "memory");
    __builtin_amdgcn_sched_barrier(0);
    __builtin_amdgcn_s_barrier();
    __builtin_amdgcn_sched_barrier(0);
    if (kt + 1 >= nK) break;
    // odd step: compute buf1/bR1, prefetch kt+2 -> buf0/bR0
    if (kt + 2 < nK) {
      stageA(0, (kt + 2) << 6);
      loadB(bR0, kt + 2);
      __builtin_amdgcn_sched_barrier(0);
      asm volatile("s_waitcnt vmcnt(6)" ::: "memory");
    } else {
      __builtin_amdgcn_sched_barrier(0);
      asm volatile("s_waitcnt vmcnt(0)" ::: "memory");
    }
    __builtin_amdgcn_sched_barrier(0);
    __builtin_amdgcn_s_barrier();
    __builtin_amdgcn_sched_barrier(0);
    compute(1, bR1);
    asm volatile("s_waitcnt lgkmcnt(0)" ::: "memory");
    __builtin_amdgcn_sched_barrier(0);
    __builtin_amdgcn_s_barrier();
    __builtin_amdgcn_sched_barrier(0);
  }
  // epilogue: bias + residual, fp32 out
#pragma unroll
  for (int tj = 0; tj < 2; ++tj) {
    int col = n0 + wn + tj * 16 + l16;
    float bv = bias[col];
#pragma unroll
    for (int ti = 0; ti < 2; ++ti) {
#pragma unroll
      for (int r = 0; r < 4; ++r) {
        int rowg = m0 + wm + ti * 16 + quad * 4 + r;
        float vv = acc[ti][tj][r] + bv + res[(size_t)rowg * N + col];
        out[(size_t)rowg * N + col] = vv;
      }
    }
  }
}

// ---------------- 256x256 8-phase GEMM (T3+T4+T5), bf16 out + bias (+relu) --
// R17: fragments register-resident across reusing phases (24 b128/K-tile).
__global__ __launch_bounds__(512, 2) void gemm256(
    const unsigned short* __restrict__ A, const unsigned short* __restrict__ Bt,
    const float* __restrict__ bias, unsigned short* __restrict__ out,
    bool relu, int M, int N, int K) {
  __shared__ __align__(16) unsigned short lsA[2][2][128 * 64];
  __shared__ __align__(16) unsigned short lsB[2][2][128 * 64];
  int tid = threadIdx.x;
  int lane = tid & 63, w = tid >> 6, quad = lane >> 4, l16 = lane & 15;
  int wr = w >> 2, wc = w & 3;
  int bidl = blockIdx.y * (int)gridDim.x + blockIdx.x;
  int swz = xcd_swz(bidl, (int)(gridDim.x * gridDim.y));
  int m0 = (swz / (int)gridDim.x) * 256, n0 = (swz % (int)gridDim.x) * 256;
  f4v acc[8][4] = {};
  s8v afh[2][4][2];  // held A fragments [MH][tm][s]
  s8v bfh[2][2][2];  // held B fragments [NH][tn][s]

  auto stageA = [&](int par, int h, int kt) {
#pragma unroll
    for (int i = 0; i < 2; ++i) {
      int cb = w * 128 + i * 64;
      int ci = cb + lane;
      int r = ci >> 3, c = ci & 7;
      int cs = c ^ (r & 7);
      int grow = ((r >> 6) << 7) + h * 64 + (r & 63);
      async16(A + (size_t)(m0 + grow) * K + kt * 64 + cs * 8,
              &lsA[par][h][cb * 8]);
    }
  };
  auto stageB = [&](int par, int h, int kt) {
#pragma unroll
    for (int i = 0; i < 2; ++i) {
      int cb = w * 128 + i * 64;
      int ci = cb + lane;
      int r = ci >> 3, c = ci & 7;
      int cs = c ^ (r & 7);
      int gn = ((r >> 5) << 6) + h * 32 + (r & 31);
      async16(Bt + (size_t)(n0 + gn) * K + kt * 64 + cs * 8,
              &lsB[par][h][cb * 8]);
    }
  };

#define PHASE(PAR, MH, NH, RA, RB, STAGE_STMT, VMN)                            \
  {                                                                            \
    if (RA) {                                                                  \
      _Pragma("unroll") for (int tm = 0; tm < 4; ++tm) {                       \
        int lr = wr * 64 + tm * 16 + l16;                                      \
        _Pragma("unroll") for (int s = 0; s < 2; ++s) {                        \
          int ac = (s * 4 + quad) ^ (lr & 7);                                  \
          afh[MH][tm][s] = *(const s8v*)(&lsA[PAR][MH][lr * 64 + ac * 8]);     \
        }                                                                      \
      }                                                                        \
    }                                                                          \
    if (RB) {                                                                  \
      _Pragma("unroll") for (int tn = 0; tn < 2; ++tn) {                       \
        int rb = wc * 32 + tn * 16 + l16;                                      \
        _Pragma("unroll") for (int s = 0; s < 2; ++s) {                        \
          int bc = (s * 4 + quad) ^ (rb & 7);                                  \
          bfh[NH][tn][s] = *(const s8v*)(&lsB[PAR][NH][rb * 64 + bc * 8]);     \
        }                                                                      \
      }                                                                        \
    }                                                                          \
    STAGE_STMT;                                                                \
    __builtin_amdgcn_sched_barrier(0);                                         \
    __builtin_amdgcn_s_barrier();                                              \
    __builtin_amdgcn_sched_barrier(0);                                         \
    __builtin_amdgcn_s_setprio(1);                                             \
    _Pragma("unroll") for (int s = 0; s < 2; ++s)                              \
      _Pragma("unroll") for (int tm = 0; tm < 4; ++tm)                         \
        _Pragma("unroll") for (int tn = 0; tn < 2; ++tn)                       \
          acc[MH * 4 + tm][NH * 2 + tn] =                                      \
              __builtin_amdgcn_mfma_f32_16x16x32_bf16(                         \
                  afh[MH][tm][s], bfh[NH][tn][s],                              \
                  acc[MH * 4 + tm][NH * 2 + tn], 0, 0, 0);                     \
    __builtin_amdgcn_s_setprio(0);                                             \
    __builtin_amdgcn_sched_barrier(0);                                         \
    if (VMN == 4) { asm volatile("s_waitcnt vmcnt(4)" ::: "memory"); }         \
    else if (VMN == 0) { asm volatile("s_waitcnt vmcnt(0)" ::: "memory"); }    \
    __builtin_amdgcn_sched_barrier(0);                                         \
    __builtin_amdgcn_s_barrier();                                              \
    __builtin_amdgcn_sched_barrier(0);                                         \
  }

  int nT = K >> 6;  // assumes nT even, >= 4
  stageA(0, 0, 0); stageB(0, 0, 0); stageA(0, 1, 0); stageB(0, 1, 0);
  stageB(1, 0, 1); stageA(1, 0, 1);
  asm volatile("s_waitcnt vmcnt(4)" ::: "memory");
  __builtin_amdgcn_sched_barrier(0);
  __builtin_amdgcn_s_barrier();
  __builtin_amdgcn_sched_barrier(0);

  for (int t = 0; t < nT; t += 2) {
    bool s2 = (t + 2) < nT, s3 = (t + 3) < nT;
    PHASE(0, 0, 0, 1, 1, { stageA(1, 1, t + 1); }, -1)                 // ph1
    PHASE(0, 1, 0, 1, 0, { stageB(1, 1, t + 1); }, -1)                 // ph2
    PHASE(0, 0, 1, 0, 1, { if (s2) stageB(0, 0, t + 2); }, -1)         // ph3
    PHASE(0, 1, 1, 0, 0, { if (s2) stageA(0, 0, t + 2); }, (s2 ? 4 : 0)) // ph4
    PHASE(1, 0, 0, 1, 1, { if (s2) stageA(0, 1, t + 2); }, -1)         // ph5
    PHASE(1, 1, 0, 1, 0, { if (s2) stageB(0, 1, t + 2); }, -1)         // ph6
    PHASE(1, 0, 1, 0, 1, { if (s3) stageB(1, 0, t + 3); }, -1)         // ph7
    PHASE(1, 1, 1, 0, 0, { if (s3) stageA(1, 0, t + 3); }, (s3 ? 4 : 0)) // ph8
  }
#undef PHASE

#pragma unroll
  for (int mi = 0; mi < 8; ++mi) {
    int mh = mi >> 2, tm = mi & 3;
#pragma unroll
    for (int nj = 0; nj < 4; ++nj) {
      int nh = nj >> 1, tn = nj & 1;
      int col = n0 + wc * 64 + nh * 32 + tn * 16 + l16;
      float bv = bias[col];
#pragma unroll
      for (int r = 0; r < 4; ++r) {
        int rowg = m0 + wr * 128 + mh * 64 + tm * 16 + quad * 4 + r;
        float vv = acc[mi][nj][r] + bv;
        if (relu) vv = fmaxf(vv, 0.f);
        out[(size_t)rowg * N + col] = f2b(vv);
      }
    }
  }
}

// ---------------- proj GEMM with fused attention-combine A-staging ----------
__global__ __launch_bounds__(256) void gemm_proj(
    const unsigned short* __restrict__ Opart, const float* __restrict__ lpart,
    const unsigned short* __restrict__ Bt, const float* __restrict__ bias,
    const float* __restrict__ res, float* __restrict__ out, int M, int N, int K) {
  __shared__ __align__(16) unsigned short lsA[2][64 * 64];
  __shared__ __align__(16) unsigned short lsB[2][64 * 64];
  int tid = threadIdx.x;
  int lane = tid & 63, w = tid >> 6, quad = lane >> 4, l16 = lane & 15;
  int bidl = blockIdx.y * (int)gridDim.x + blockIdx.x;
  int swz = xcd_swz(bidl, (int)(gridDim.x * gridDim.y));
  int m0 = (swz / (int)gridDim.x) * 64, n0 = (swz % (int)gridDim.x) * 64;
  int wm = (w >> 1) * 32, wn = (w & 1) * 32;
  f4v acc[2][2] = {};

  int ci_[2], csA[2], mA[2], b2A[2], lA[2];
#pragma unroll
  for (int i = 0; i < 2; ++i) {
    int cb = w * 128 + i * 64;
    int ci = cb + lane;
    int row = ci >> 3, c = ci & 7;
    ci_[i] = ci; csA[i] = c ^ (row & 7);
    mA[i] = m0 + row; b2A[i] = mA[i] >> 11; lA[i] = mA[i] & 2047;
  }
  s8v o0r[2], o1r[2];
  float lsr0[2], lsr1[2];
  auto issueA = [&](int kt) {
#pragma unroll
    for (int i = 0; i < 2; ++i) {
      const unsigned short* pa =
          Opart + (size_t)mA[i] * D_MODEL + kt * 64 + csA[i] * 8;
      o0r[i] = *(const s8v*)pa;
      o1r[i] = *(const s8v*)(pa + (size_t)MROWS * D_MODEL);
      size_t lidx = ((size_t)b2A[i] * NH + kt) * SEQ + lA[i];
      lsr0[i] = lpart[lidx];
      lsr1[i] = lpart[(size_t)BATCH * NH * SEQ + lidx];
    }
  };
  auto issueB = [&](int bsel, int ktE) {
#pragma unroll
    for (int i = 0; i < 2; ++i) {
      int cb = w * 128 + i * 64;
      int ci = cb + lane;
      int row = ci >> 3, c = ci & 7;
      int cs = c ^ (row & 7);
      async16(Bt + (size_t)(n0 + row) * K + ktE + cs * 8, &lsB[bsel][cb * 8]);
    }
  };
  auto combineWrite = [&](int bsel) {
#pragma unroll
    for (int i = 0; i < 2; ++i) {
      float inv = KH_ISCALE / (lsr0[i] + lsr1[i]);
      float f[8];
#pragma unroll
      for (int j = 0; j < 8; ++j)
        f[j] = (b2f((unsigned short)o0r[i][j]) +
                b2f((unsigned short)o1r[i][j])) * inv;
      s4v lo = cvt4(f[0], f[1], f[2], f[3]);
      s4v hi = cvt4(f[4], f[5], f[6], f[7]);
      s8v vv = {lo[0], lo[1], lo[2], lo[3], hi[0], hi[1], hi[2], hi[3]};
      *(s8v*)(&lsA[bsel][ci_[i] * 8]) = vv;
    }
  };

  issueA(0); issueB(0, 0);
  __builtin_amdgcn_sched_barrier(0);
  asm volatile("s_waitcnt vmcnt(2)" ::: "memory");
  __builtin_amdgcn_sched_barrier(0);
  combineWrite(0);
  asm volatile("s_waitcnt lgkmcnt(0)" ::: "memory");
  __builtin_amdgcn_sched_barrier(0);

  int nK = K >> 6;
  for (int kt = 0; kt < nK; ++kt) {
    int b = kt & 1;
    if (kt + 1 < nK) {
      issueA(kt + 1); issueB(b ^ 1, (kt + 1) << 6);
      __builtin_amdgcn_sched_barrier(0);
      asm volatile("s_waitcnt vmcnt(10)" ::: "memory");
    } else {
      __builtin_amdgcn_sched_barrier(0);
      asm volatile("s_waitcnt vmcnt(0)" ::: "memory");
    }
    __builtin_amdgcn_sched_barrier(0);
    __builtin_amdgcn_s_barrier();
    __builtin_amdgcn_sched_barrier(0);
#pragma unroll
    for (int s = 0; s < 2; ++s) {
      s8v af[2], bf[2];
#pragma unroll
      for (int t = 0; t < 2; ++t) {
        int am = wm + t * 16 + l16;
        int ac = (s * 4 + quad) ^ (am & 7);
        af[t] = *(const s8v*)(&lsA[b][am * 64 + ac * 8]);
      }
#pragma unroll
      for (int t = 0; t < 2; ++t) {
        int bn = wn + t * 16 + l16;
        int bc = (s * 4 + quad) ^ (bn & 7);
        bf[t] = *(const s8v*)(&lsB[b][bn * 64 + bc * 8]);
      }
#pragma unroll
      for (int ti = 0; ti < 2; ++ti)
#pragma unroll
        for (int tj = 0; tj < 2; ++tj)
          acc[ti][tj] = __builtin_amdgcn_mfma_f32_16x16x32_bf16(
              af[ti], bf[tj], acc[ti][tj], 0, 0, 0);
    }
    if (kt + 1 < nK) {
      __builtin_amdgcn_sched_barrier(0);
      asm volatile("s_waitcnt vmcnt(2)" ::: "memory");
      __builtin_amdgcn_sched_barrier(0);
      combineWrite(b ^ 1);
    }
    asm volatile("s_waitcnt lgkmcnt(0)" ::: "memory");
    __builtin_amdgcn_sched_barrier(0);
    __builtin_amdgcn_s_barrier();
    __builtin_amdgcn_sched_barrier(0);
  }
#pragma unroll
  for (int tj = 0; tj < 2; ++tj) {
    int col = n0 + wn + tj * 16 + l16;
    float bv = bias[col];
#pragma unroll
    for (int ti = 0; ti < 2; ++ti) {
#pragma unroll
      for (int r = 0; r < 4; ++r) {
        int rowg = m0 + wm + ti * 16 + quad * 4 + r;
        float vv = acc[ti][tj][r] + bv + res[(size_t)rowg * N + col];
        out[(size_t)rowg * N + col] = vv;
      }
    }
  }
}

// ---------------- fused flash attention, tr-read V, register-P, XCD-local ---
__global__ __launch_bounds__(256) void flash_k(
    const unsigned short* __restrict__ kh,
    unsigned short* __restrict__ Opart, float* __restrict__ lpart) {
  __shared__ __align__(16) unsigned short lsK[2][8192];  // 2x16KB subtiled
  int tid = threadIdx.x;
  int lane = tid & 63, w = tid >> 6, quad = lane >> 4, l16 = lane & 15;
  int split = blockIdx.x, bh = blockIdx.y, qb = blockIdx.z;
  const unsigned short* khB = kh + (size_t)bh * SEQ * DH;
  unsigned short* Op = Opart + (size_t)split * MROWS * D_MODEL;
  float* lp = lpart + (size_t)split * BATCH * NH * SEQ;
  s8v aQ[2][2];
#pragma unroll
  for (int g = 0; g < 2; ++g) {
    int q = qb * 128 + w * 32 + g * 16 + l16;
#pragma unroll
    for (int s = 0; s < 2; ++s)
      aQ[g][s] = *(const s8v*)(khB + (size_t)q * DH + s * 32 + quad * 8);
  }
  const s8v vone8 = {(short)0x3F80, (short)0x3F80, (short)0x3F80, (short)0x3F80,
                     (short)0x3F80, (short)0x3F80, (short)0x3F80, (short)0x3F80};
  f4v accO[2][4] = {};
  f4v accL[2] = {};

  auto stageK = [&](int bsel, int key0) {
#pragma unroll
    for (int i = 0; i < 4; ++i) {
      int ci = w * 256 + i * 64 + lane;
      async16(khB + (size_t)(key0 + ((ci >> 1) & 127)) * DH +
                  (ci >> 8) * 16 + (ci & 1) * 8,
              &lsK[bsel][(w * 256 + i * 64) * 8]);
    }
  };
  lds_cp ls0 = (lds_cp)&lsK[0][0];
  lds_cp trb = ls0 + quad * 64 + l16 * 4;  // elements

  stageK(0, split * 1024);
  for (int kt8 = 0; kt8 < 8; ++kt8) {
    int b = kt8 & 1;
    if (kt8 + 1 < 8) {
      stageK(b ^ 1, split * 1024 + (kt8 + 1) * 128);
      asm volatile("s_waitcnt vmcnt(4)" ::: "memory");
    } else {
      asm volatile("s_waitcnt vmcnt(0)" ::: "memory");
    }
    __builtin_amdgcn_sched_barrier(0);
    __builtin_amdgcn_s_barrier();
    __builtin_amdgcn_sched_barrier(0);
#pragma unroll
    for (int half = 0; half < 2; ++half) {
      f4v accST[2][4] = {};
#pragma unroll
      for (int s = 0; s < 2; ++s) {
#pragma unroll
        for (int tj = 0; tj < 4; ++tj) {
          s8v kf = *(const s8v*)(&lsK[b][(2 * s + (quad >> 1)) * 2048 +
                                         (half * 64 + tj * 16 + l16) * 16 +
                                         (quad & 1) * 8]);
#pragma unroll
          for (int g = 0; g < 2; ++g)
            accST[g][tj] = __builtin_amdgcn_mfma_f32_16x16x32_bf16(
                kf, aQ[g][s], accST[g][tj], 0, 0, 0);
        }
      }
      s4v pprev[2];
#pragma unroll
      for (int tj = 0; tj < 4; ++tj) {
        s4v vt[4];
#pragma unroll
        for (int db = 0; db < 4; ++db)
          vt[db] = tr16(trb + b * 8192 + db * 2048 + half * 1024 + tj * 256);
        s4v pf[2];
#pragma unroll
        for (int g = 0; g < 2; ++g) {
          float p0 = xp2(accST[g][tj][0]);
          float p1 = xp2(accST[g][tj][1]);
          float p2 = xp2(accST[g][tj][2]);
          float p3 = xp2(accST[g][tj][3]);
          pf[g] = cvt4(p0, p1, p2, p3);
        }
        if (tj & 1) {
#pragma unroll
          for (int g = 0; g < 2; ++g) {
            s8v pp = {pprev[g][0], pprev[g][1], pprev[g][2], pprev[g][3],
                      pf[g][0], pf[g][1], pf[g][2], pf[g][3]};
            accL[g] = __builtin_amdgcn_mfma_f32_16x16x32_bf16(
                pp, vone8, accL[g], 0, 0, 0);  // B=1: k-position irrelevant
          }
        } else {
#pragma unroll
          for (int g = 0; g < 2; ++g) pprev[g] = pf[g];
        }
        asm volatile("s_waitcnt lgkmcnt(0)" ::: "memory");  // tr reads landed
        __builtin_amdgcn_sched_barrier(0);
#pragma unroll
        for (int db = 0; db < 4; ++db)
#pragma unroll
          for (int g = 0; g < 2; ++g)
            accO[g][db] = mfma16(pf[g], vt[db], accO[g][db]);
      }
    }
    asm volatile("s_waitcnt lgkmcnt(0)" ::: "memory");
    __builtin_amdgcn_sched_barrier(0);
    __builtin_amdgcn_s_barrier();
    __builtin_amdgcn_sched_barrier(0);
  }
  int b = bh >> 4, h = bh & 15;
#pragma unroll
  for (int g = 0; g < 2; ++g) {
    if (l16 == 0) {
#pragma unroll
      for (int r = 0; r < 4; ++r) {
        int q = qb * 128 + w * 32 + g * 16 + quad * 4 + r;
        lp[(size_t)bh * SEQ + q] = accL[g][r];
      }
    }
#pragma unroll
    for (int r = 0; r < 4; ++r) {
      int l = qb * 128 + w * 32 + g * 16 + quad * 4 + r;
#pragma unroll
      for (int db = 0; db < 4; ++db) {
        int d = db * 16 + l16;
        Op[((size_t)(b * SEQ + l)) * D_MODEL + h * DH + d] = f2b(accO[g][db][r]);
      }
    }
  }
}

// ---------------------------------------------------------------------------
extern "C" void kernel_launch(void* const* d_in, const int* in_sizes, int n_in,
                              void* d_out, int out_size, void* d_ws, size_t ws_size,
                              hipStream_t stream) {
  (void)in_sizes; (void)n_in; (void)out_size;
  const float* x      = (const float*)d_in[0];
  const float* w_attn = (const float*)d_in[1];
  const float* b_attn = (const float*)d_in[2];
  const float* w_proj = (const float*)d_in[3];
  const float* b_proj = (const float*)d_in[4];
  const float* ln1_g  = (const float*)d_in[5];
  const float* ln1_b  = (const float*)d_in[6];
  const float* ln2_g  = (const float*)d_in[7];
  const float* ln2_b  = (const float*)d_in[8];
  const float* w_fc1  = (const float*)d_in[9];
  const float* b_fc1  = (const float*)d_in[10];
  const float* w_fc2  = (const float*)d_in[11];
  const float* b_fc2  = (const float*)d_in[12];

  char* ws = (char*)d_ws;
  unsigned short* Opart = (unsigned short*)ws;                         // [0,16M)
  unsigned short* kh    = (unsigned short*)(ws + (size_t)(16u << 20)); // [16,24)
  float*          x1    = (float*)(ws + (size_t)(32u << 20));          // [32,48)
  unsigned short* hbuf  = (unsigned short*)(ws + (size_t)(48u << 20)); // [48,56)
  float*          lpart = (float*)(ws + (size_t)(48u << 20));  // h1 dead by flash
  float* outf = (float*)d_out;
  bool big_ws = ws_size >= ((size_t)72u << 20);

  unsigned short* wTk;
  unsigned short* wTp;
  unsigned short* wTf1;
  unsigned short* wTf2;
  unsigned short* fc1o;
  if (big_ws) {
    wTk  = (unsigned short*)(ws + (size_t)(56u << 20));
    wTp  = wTk;
    wTf1 = wTk;
    wTf2 = (unsigned short*)(ws + (size_t)(64u << 20));
    fc1o = (unsigned short*)ws;                            // [0,32): Op/kh dead
  } else {
    wTk  = (unsigned short*)ws;
    wTp  = (unsigned short*)(ws + (size_t)(24u << 20));    // free (was khT)
    wTf1 = (unsigned short*)ws;
    wTf2 = (unsigned short*)(ws + (size_t)(8u << 20));
    fc1o = kh;                                             // [16,32): chunked 16MB
  }

  dim3 blk(256);
  // 1. h1 = LN1(x)
  hipLaunchKernelGGL(ln_kernel, dim3(MROWS), blk, 0, stream, x, ln1_g, ln1_b, hbuf);
  // 2. wTk = (w_attn[:, 1024:2048])^T
  hipLaunchKernelGGL(transpose_b<float>, dim3(16, 16, 1), blk, 0, stream,
                     w_attn + 1024, wTk, 3 * D_MODEL, D_MODEL, 0LL, 0LL);
  // 3. kh[b,h,l,d] = (h1 @ w_k + b_k) * KH_SCALE  (R17 gemm_bt, reverted)
  hipLaunchKernelGGL((gemm_bt<0, false, true, 0, 64, 64>), dim3(16, 64), blk, 0,
                     stream, hbuf, wTk, b_attn + 1024, nullptr, (void*)kh,
                     MROWS, D_MODEL, D_MODEL);
  // 4. flash (tr-read V; khT eliminated) -> bf16 partials + l partials
  hipLaunchKernelGGL(flash_k, dim3(2, 32, SEQ / 128), blk, 0, stream,
                     kh, Opart, lpart);
  // 5. wTp = w_proj^T ; x1 = combine(Opart,lpart) @ w_proj + b + x  (fused)
  hipLaunchKernelGGL(transpose_b<float>, dim3(16, 16, 1), blk, 0, stream,
                     w_proj, wTp, D_MODEL, D_MODEL, 0LL, 0LL);
  hipLaunchKernelGGL(gemm_proj, dim3(16, 64), blk, 0, stream,
                     Opart, lpart, wTp, b_proj, x, x1,
                     MROWS, D_MODEL, D_MODEL);
  // 6. h2 = LN2(x1)
  hipLaunchKernelGGL(ln_kernel, dim3(MROWS), blk, 0, stream, x1, ln2_g, ln2_b, hbuf);
  // 7. wTf1 = w_fc1^T ; wTf2 = w_fc2^T
  hipLaunchKernelGGL(transpose_b<float>, dim3(64, 16, 1), blk, 0, stream,
                     w_fc1, wTf1, 4 * D_MODEL, D_MODEL, 0LL, 0LL);
  hipLaunchKernelGGL(transpose_b<float>, dim3(16, 64, 1), blk, 0, stream,
                     w_fc2, wTf2, D_MODEL, 4 * D_MODEL, 0LL, 0LL);
  // 8/9. FFN: FC1 8-phase 256^2; FC2 B-in-registers (gemm_fc2)
  if (big_ws) {
    hipLaunchKernelGGL(gemm256, dim3(16, 16), dim3(512), 0, stream,
                       hbuf, wTf1, b_fc1, fc1o, true,
                       MROWS, 4 * D_MODEL, D_MODEL);
    hipLaunchKernelGGL(gemm_fc2, dim3(16, 64), blk, 0, stream,
                       fc1o, wTf2, b_fc2, x1, outf,
                       MROWS, D_MODEL, 4 * D_MODEL);
  } else {
    for (int c = 0; c < 2; ++c) {
      const unsigned short* h2c = hbuf + (size_t)c * 2048 * D_MODEL;
      const float* x1c = x1 + (size_t)c * 2048 * D_MODEL;
      float* outc = outf + (size_t)c * 2048 * D_MODEL;
      hipLaunchKernelGGL((gemm_bt<0, true, false, 0, 128, 64>), dim3(64, 16), blk, 0,
                         stream, h2c, wTf1, b_fc1, nullptr, (void*)fc1o,
                         2048, 4 * D_MODEL, D_MODEL);
      hipLaunchKernelGGL(gemm_fc2, dim3(16, 32), blk, 0, stream,
                         fc1o, wTf2, b_fc2, x1c, outc,
                         2048, D_MODEL, 4 * D_MODEL);
    }
  }
}

// Round 12
// 323.070 us; speedup vs baseline: 1.2353x; 1.2353x over previous
//
#include <hip/hip_runtime.h>

// ---------------------------------------------------------------------------
// Transformer block on MI355X. fp32 I/O (per reference), bf16 MFMA internals,
// fp32 accumulation/residuals.
// R21: (a) revert gemm_fc2 (R19/R20 FAILED: per-lane scattered B-loads, 16B
// used per 64B sector at 8KB row stride -> FETCH 123MB, 142us) back to
// staged GEMMs. (b) FC2 = gemm_bt2i: R18's wave-split-K with INTERLEAVED K
// (group g takes steps 2t+g). R18's +10us regression == its FETCH excess
// (33MB ~= 19us HBM): disjoint K-halves doubled the per-XCD hot A window
// past L2. Interleaving makes both groups walk adjacent K-tiles -> per-block
// footprint identical to gemm_bt, while the barrier chain still halves
// (64 -> 32 iterations) at 16 waves/CU (2 blk x 8 waves, 64KB LDS).
// Everything else = R17-exact (315.2us best): kh/proj 2-phase gemm_bt 64^2,
// FC1 8-phase 256^2 w/ register-resident fragments, flash tr-read V.
// R15/16: flash tr-read V, lsK dbuf, accL K=32 pairs. R13: XCD-chunk
// swizzle, fused combine-proj. R10: kexp in kh, cvt_pk, bare exp2.
// ws layout (56MB min, 72MB preferred):
//   [0,16M)  Opart | big: fc1o [0,32M) after proj
//   [16,24M) kh    | fallback: fc1o [16,32M)
//   [24,32M) (free; was khT)
//   [32,48M) x1    [48,56M) hbuf + lpart during flash
//   [56,64M) wT1 (big), [64,72M) wT2 (big)
// ---------------------------------------------------------------------------

typedef __attribute__((ext_vector_type(8))) short s8v;  // 8 bf16 raw
typedef __attribute__((ext_vector_type(4))) short s4v;  // 4 bf16 raw
typedef __attribute__((ext_vector_type(4))) float f4v;  // mfma accumulator

#define D_MODEL 1024
#define SEQ 2048
#define BATCH 2
#define NH 16
#define DH 64
#define MROWS (BATCH * SEQ)

#define KH_SCALE 0.42466088f
#define KH_ISCALE 2.3548200f

__device__ __forceinline__ float b2f(unsigned short u) {
  union { unsigned int i; float f; } v; v.i = ((unsigned int)u) << 16; return v.f;
}
__device__ __forceinline__ unsigned short f2b(float f) {
  unsigned int i = __builtin_bit_cast(unsigned int, f);
  unsigned int r = (i + 0x7fffu + ((i >> 16) & 1u)) >> 16;  // RNE
  return (unsigned short)r;
}
// async global->LDS, 16B/lane; dest = wave-uniform base + lane*16 (m104/m108)
__device__ __forceinline__ void async16(const void* g, void* l) {
  __builtin_amdgcn_global_load_lds(
      (const __attribute__((address_space(1))) unsigned int*)g,
      (__attribute__((address_space(3))) unsigned int*)l, 16, 0, 0);
}
__device__ __forceinline__ unsigned short cvt_b(float f) { return f2b(f); }
__device__ __forceinline__ unsigned short cvt_b(unsigned short u) { return u; }

__device__ __forceinline__ float xp2(float x) {
#if __has_builtin(__builtin_amdgcn_exp2f)
  return __builtin_amdgcn_exp2f(x);
#else
  return exp2f(x);
#endif
}

// 4x f32 -> packed bf16 s4v via v_cvt_pk_bf16_f32 (RNE, 2 instructions).
__device__ __forceinline__ s4v cvt4(float a, float b, float c, float d) {
  unsigned int lo, hi;
  asm("v_cvt_pk_bf16_f32 %0, %1, %2" : "=v"(lo) : "v"(a), "v"(b));
  asm("v_cvt_pk_bf16_f32 %0, %1, %2" : "=v"(hi) : "v"(c), "v"(d));
  union { unsigned long long u; s4v v; } u;
  u.u = ((unsigned long long)hi << 32) | (unsigned long long)lo;
  return u.v;
}

#if __has_builtin(__builtin_amdgcn_mfma_f32_16x16x16_bf16)
__device__ __forceinline__ f4v mfma16(s4v a, s4v b, f4v c) {
  return __builtin_amdgcn_mfma_f32_16x16x16_bf16(a, b, c, 0, 0, 0);
}
#elif __has_builtin(__builtin_amdgcn_mfma_f32_16x16x16bf16_1k)
__device__ __forceinline__ f4v mfma16(s4v a, s4v b, f4v c) {
  return __builtin_amdgcn_mfma_f32_16x16x16bf16_1k(a, b, c, 0, 0, 0);
}
#else
__device__ __forceinline__ f4v mfma16(s4v a, s4v b, f4v c) {
  s8v aa = {a[0], a[1], a[2], a[3], 0, 0, 0, 0};
  s8v bb = {b[0], b[1], b[2], b[3], 0, 0, 0, 0};
  return __builtin_amdgcn_mfma_f32_16x16x32_bf16(aa, bb, c, 0, 0, 0);
}
#endif

// LDS transpose-read: supply the natural per-lane ds_read_b64 address
// (base + lane*8B); each 16-lane group's 128B region is delivered
// column-major: lane l gets column (l&15) of its 4x16 bf16 tile (m156/m162).
typedef __attribute__((address_space(3))) const unsigned short* lds_cp;
__device__ __forceinline__ s4v tr16(lds_cp p) {
  unsigned long long d;
  asm volatile("ds_read_b64_tr_b16 %0, %1" : "=v"(d) : "v"(p));
  return __builtin_bit_cast(s4v, d);
}

// XCD-chunked logical block id (T1); bijective only when nwg%8==0.
__device__ __forceinline__ int xcd_swz(int bidl, int nwg) {
  return (nwg & 7) ? bidl : ((bidl & 7) * (nwg >> 3) + (bidl >> 3));
}

// ---------------- LayerNorm: fp32 in -> bf16 out, one block per row ---------
__global__ __launch_bounds__(256) void ln_kernel(
    const float* __restrict__ x, const float* __restrict__ g,
    const float* __restrict__ bb, unsigned short* __restrict__ out) {
  int row = blockIdx.x;
  int t = threadIdx.x;
  const float* xr = x + (size_t)row * D_MODEL;
  float v[4];
  float s = 0.f, s2 = 0.f;
#pragma unroll
  for (int i = 0; i < 4; ++i) {
    float f = xr[t + 256 * i];
    v[i] = f; s += f; s2 += f * f;
  }
#pragma unroll
  for (int off = 1; off < 64; off <<= 1) {
    s += __shfl_xor(s, off, 64);
    s2 += __shfl_xor(s2, off, 64);
  }
  __shared__ float red[8];
  if ((t & 63) == 0) { red[t >> 6] = s; red[4 + (t >> 6)] = s2; }
  __syncthreads();
  s = red[0] + red[1] + red[2] + red[3];
  s2 = red[4] + red[5] + red[6] + red[7];
  float mu = s * (1.f / D_MODEL);
  float var = s2 * (1.f / D_MODEL) - mu * mu;
  float rstd = rsqrtf(var + 1e-5f);
#pragma unroll
  for (int i = 0; i < 4; ++i) {
    int c = t + 256 * i;
    float h = (v[i] - mu) * rstd * g[c] + bb[c];
    out[(size_t)row * D_MODEL + c] = f2b(h);
  }
}

// ---------------- batched 64x64 tile transpose -> bf16 ----------------------
template <typename T>
__global__ __launch_bounds__(256) void transpose_b(
    const T* __restrict__ src, unsigned short* __restrict__ dst,
    int srcStride, int dstStride, long long srcBatch, long long dstBatch) {
  __shared__ unsigned short tile[64][65];
  const T* s = src + (size_t)blockIdx.z * srcBatch;
  unsigned short* d = dst + (size_t)blockIdx.z * dstBatch;
  int n0 = blockIdx.x * 64, k0 = blockIdx.y * 64;
  for (int i = threadIdx.x; i < 4096; i += 256) {
    int k = i >> 6, n = i & 63;
    tile[k][n] = cvt_b(s[(size_t)(k0 + k) * srcStride + n0 + n]);
  }
  __syncthreads();
  for (int i = threadIdx.x; i < 4096; i += 256) {
    int n = i >> 6, k = i & 63;
    d[(size_t)(n0 + n) * dstStride + k0 + k] = tile[k][n];
  }
}

// ---------------- GEMM: C[M,N] = A[M,K] @ Bt[N,K]^T + bias (+res)(+relu) ----
// BMxBN tile, BK=64, 4 waves (2x2); 2-phase dbuf, counted vmcnt, raw barrier.
template <int RES, bool RELU, bool KH, int OUTF, int BM, int BN>
__global__ __launch_bounds__(256) void gemm_bt(
    const unsigned short* __restrict__ A, const unsigned short* __restrict__ Bt,
    const float* __restrict__ bias, const float* __restrict__ res,
    void* __restrict__ out, int M, int N, int K) {
  constexpr int MT = BM / 32;
  constexpr int NT = BN / 32;
  __shared__ __align__(16) unsigned short lsA[2][BM * 64];
  __shared__ __align__(16) unsigned short lsB[2][BN * 64];
  int tid = threadIdx.x;
  int lane = tid & 63, w = tid >> 6, quad = lane >> 4, l16 = lane & 15;
  int bidl = blockIdx.y * (int)gridDim.x + blockIdx.x;
  int swz = xcd_swz(bidl, (int)(gridDim.x * gridDim.y));
  int m0 = (swz / (int)gridDim.x) * BM, n0 = (swz % (int)gridDim.x) * BN;
  int wm = (w >> 1) * (BM / 2), wn = (w & 1) * (BN / 2);
  f4v acc[MT][NT] = {};

  auto stage = [&](int bsel, int ktE) {
#pragma unroll
    for (int i = 0; i < MT; ++i) {
      int cb = w * (BM * 2) + i * 64;
      int ci = cb + lane;
      int row = ci >> 3, c = ci & 7;
      int cs = c ^ (row & 7);
      async16(A + (size_t)(m0 + row) * K + ktE + cs * 8, &lsA[bsel][cb * 8]);
    }
#pragma unroll
    for (int i = 0; i < NT; ++i) {
      int cb = w * (BN * 2) + i * 64;
      int ci = cb + lane;
      int row = ci >> 3, c = ci & 7;
      int cs = c ^ (row & 7);
      async16(Bt + (size_t)(n0 + row) * K + ktE + cs * 8, &lsB[bsel][cb * 8]);
    }
  };

  stage(0, 0);
  int nK = K >> 6;
  for (int kt = 0; kt < nK; ++kt) {
    int b = kt & 1;
    if (kt + 1 < nK) {
      stage(b ^ 1, (kt + 1) << 6);
      if constexpr (MT + NT == 4)      asm volatile("s_waitcnt vmcnt(4)" ::: "memory");
      else if constexpr (MT + NT == 6) asm volatile("s_waitcnt vmcnt(6)" ::: "memory");
      else                             asm volatile("s_waitcnt vmcnt(8)" ::: "memory");
    } else {
      asm volatile("s_waitcnt vmcnt(0)" ::: "memory");
    }
    __builtin_amdgcn_sched_barrier(0);
    __builtin_amdgcn_s_barrier();
    __builtin_amdgcn_sched_barrier(0);
#pragma unroll
    for (int s = 0; s < 2; ++s) {
      s8v af[MT], bf[NT];
#pragma unroll
      for (int t = 0; t < MT; ++t) {
        int am = wm + t * 16 + l16;
        int ac = (s * 4 + quad) ^ (am & 7);
        af[t] = *(const s8v*)(&lsA[b][am * 64 + ac * 8]);
      }
#pragma unroll
      for (int t = 0; t < NT; ++t) {
        int bn = wn + t * 16 + l16;
        int bc = (s * 4 + quad) ^ (bn & 7);
        bf[t] = *(const s8v*)(&lsB[b][bn * 64 + bc * 8]);
      }
#pragma unroll
      for (int ti = 0; ti < MT; ++ti)
#pragma unroll
        for (int tj = 0; tj < NT; ++tj)
          acc[ti][tj] = __builtin_amdgcn_mfma_f32_16x16x32_bf16(
              af[ti], bf[tj], acc[ti][tj], 0, 0, 0);
    }
    asm volatile("s_waitcnt lgkmcnt(0)" ::: "memory");
    __builtin_amdgcn_sched_barrier(0);
    __builtin_amdgcn_s_barrier();
    __builtin_amdgcn_sched_barrier(0);
  }
#pragma unroll
  for (int tj = 0; tj < NT; ++tj) {
    int col = n0 + wn + tj * 16 + l16;
    float bv = bias[col];
#pragma unroll
    for (int ti = 0; ti < MT; ++ti) {
#pragma unroll
      for (int r = 0; r < 4; ++r) {
        int rowg = m0 + wm + ti * 16 + quad * 4 + r;
        float vv = acc[ti][tj][r] + bv;
        if (KH) vv *= KH_SCALE;
        if (RES == 2) vv += res[(size_t)rowg * N + col];
        if (RELU) vv = fmaxf(vv, 0.f);
        size_t oidx;
        if (KH) {
          int b2 = rowg >> 11, l = rowg & 2047, h = col >> 6, d = col & 63;
          oidx = (((size_t)(b2 * NH + h)) * SEQ + l) * DH + d;
        } else {
          oidx = (size_t)rowg * N + col;
        }
        if (OUTF == 0) ((unsigned short*)out)[oidx] = f2b(vv);
        else           ((float*)out)[oidx] = vv;
      }
    }
  }
}

// ---------------- interleaved wave-split-K GEMM: 64x64, 8 waves, 2 K-groups -
// R21: group g (waves 4g..4g+3) computes C-partial over K-tiles {2t+g} with
// its own LDS dbuf pair -- INTERLEAVED so both groups walk adjacent K-tiles
// (per-block A footprint == gemm_bt; fixes R18's L2 thrash, FETCH 90->57MB
// predicted). Shared barriers retire 2 K-tiles/iter (chain 64->32). 16
// waves/CU (2 blk x 8 waves, 64KB LDS). Epilogue: group1 partial -> fp32 LDS
// (dead staging space), barrier, group0 adds + bias/res; fp32 out.
template <int RES, bool RELU, bool KH, int OUTF>
__global__ __launch_bounds__(512) void gemm_bt2i(
    const unsigned short* __restrict__ A, const unsigned short* __restrict__ Bt,
    const float* __restrict__ bias, const float* __restrict__ res,
    void* __restrict__ out, int M, int N, int K) {
  __shared__ __align__(16) unsigned short lsA[2][2][64 * 64];  // [kg][par]
  __shared__ __align__(16) unsigned short lsB[2][2][64 * 64];
  int tid = threadIdx.x;
  int lane = tid & 63, w = tid >> 6, quad = lane >> 4, l16 = lane & 15;
  int kg = w >> 2, wi = w & 3;
  int bidl = blockIdx.y * (int)gridDim.x + blockIdx.x;
  int swz = xcd_swz(bidl, (int)(gridDim.x * gridDim.y));
  int m0 = (swz / (int)gridDim.x) * 64, n0 = (swz % (int)gridDim.x) * 64;
  int wm = (wi >> 1) * 32, wn = (wi & 1) * 32;
  f4v acc[2][2] = {};

  // stage K-tile (2*st + kg): 2+2 async16/wave; vmcnt(4) steady state.
  auto stage = [&](int par, int st) {
    int koff = ((st << 1) + kg) << 6;  // interleaved K assignment
#pragma unroll
    for (int i = 0; i < 2; ++i) {
      int cb = wi * 128 + i * 64;
      int ci = cb + lane;
      int row = ci >> 3, c = ci & 7;
      int cs = c ^ (row & 7);
      async16(A + (size_t)(m0 + row) * K + koff + cs * 8,
              &lsA[kg][par][cb * 8]);
    }
#pragma unroll
    for (int i = 0; i < 2; ++i) {
      int cb = wi * 128 + i * 64;
      int ci = cb + lane;
      int row = ci >> 3, c = ci & 7;
      int cs = c ^ (row & 7);
      async16(Bt + (size_t)(n0 + row) * K + koff + cs * 8,
              &lsB[kg][par][cb * 8]);
    }
  };

  stage(0, 0);
  int nS = K >> 7;  // steps per group
  for (int st = 0; st < nS; ++st) {
    int par = st & 1;
    if (st + 1 < nS) {
      stage(par ^ 1, st + 1);
      asm volatile("s_waitcnt vmcnt(4)" ::: "memory");
    } else {
      asm volatile("s_waitcnt vmcnt(0)" ::: "memory");
    }
    __builtin_amdgcn_sched_barrier(0);
    __builtin_amdgcn_s_barrier();
    __builtin_amdgcn_sched_barrier(0);
#pragma unroll
    for (int s = 0; s < 2; ++s) {
      s8v af[2], bf[2];
#pragma unroll
      for (int t = 0; t < 2; ++t) {
        int am = wm + t * 16 + l16;
        int ac = (s * 4 + quad) ^ (am & 7);
        af[t] = *(const s8v*)(&lsA[kg][par][am * 64 + ac * 8]);
      }
#pragma unroll
      for (int t = 0; t < 2; ++t) {
        int bn = wn + t * 16 + l16;
        int bc = (s * 4 + quad) ^ (bn & 7);
        bf[t] = *(const s8v*)(&lsB[kg][par][bn * 64 + bc * 8]);
      }
#pragma unroll
      for (int ti = 0; ti < 2; ++ti)
#pragma unroll
        for (int tj = 0; tj < 2; ++tj)
          acc[ti][tj] = __builtin_amdgcn_mfma_f32_16x16x32_bf16(
              af[ti], bf[tj], acc[ti][tj], 0, 0, 0);
    }
    asm volatile("s_waitcnt lgkmcnt(0)" ::: "memory");
    __builtin_amdgcn_sched_barrier(0);
    __builtin_amdgcn_s_barrier();
    __builtin_amdgcn_sched_barrier(0);
  }

  // cross-group reduction: group1 partial -> fp32 LDS (staging space dead)
  float* red = (float*)&lsA[0][0][0];  // 64x64 fp32 = 16KB
  if (kg == 1) {
#pragma unroll
    for (int tj = 0; tj < 2; ++tj)
#pragma unroll
      for (int ti = 0; ti < 2; ++ti)
#pragma unroll
        for (int r = 0; r < 4; ++r)
          red[(wm + ti * 16 + quad * 4 + r) * 64 + wn + tj * 16 + l16] =
              acc[ti][tj][r];
  }
  asm volatile("s_waitcnt lgkmcnt(0)" ::: "memory");
  __builtin_amdgcn_sched_barrier(0);
  __builtin_amdgcn_s_barrier();
  __builtin_amdgcn_sched_barrier(0);
  if (kg == 0) {
#pragma unroll
    for (int tj = 0; tj < 2; ++tj) {
      int col = n0 + wn + tj * 16 + l16;
      float bv = bias[col];
#pragma unroll
      for (int ti = 0; ti < 2; ++ti) {
#pragma unroll
        for (int r = 0; r < 4; ++r) {
          int rowl = wm + ti * 16 + quad * 4 + r;
          int rowg = m0 + rowl;
          float vv = acc[ti][tj][r] + red[rowl * 64 + wn + tj * 16 + l16] + bv;
          if (KH) vv *= KH_SCALE;
          if (RES == 2) vv += res[(size_t)rowg * N + col];
          if (RELU) vv = fmaxf(vv, 0.f);
          size_t oidx;
          if (KH) {
            int b2 = rowg >> 11, l = rowg & 2047, h = col >> 6, d = col & 63;
            oidx = (((size_t)(b2 * NH + h)) * SEQ + l) * DH + d;
          } else {
            oidx = (size_t)rowg * N + col;
          }
          if (OUTF == 0) ((unsigned short*)out)[oidx] = f2b(vv);
          else           ((float*)out)[oidx] = vv;
        }
      }
    }
  }
}

// ---------------- 256x256 8-phase GEMM (T3+T4+T5), bf16 out + bias (+relu) --
// R17: fragments register-resident across reusing phases (24 b128/K-tile).
__global__ __launch_bounds__(512, 2) void gemm256(
    const unsigned short* __restrict__ A, const unsigned short* __restrict__ Bt,
    const float* __restrict__ bias, unsigned short* __restrict__ out,
    bool relu, int M, int N, int K) {
  __shared__ __align__(16) unsigned short lsA[2][2][128 * 64];
  __shared__ __align__(16) unsigned short lsB[2][2][128 * 64];
  int tid = threadIdx.x;
  int lane = tid & 63, w = tid >> 6, quad = lane >> 4, l16 = lane & 15;
  int wr = w >> 2, wc = w & 3;
  int bidl = blockIdx.y * (int)gridDim.x + blockIdx.x;
  int swz = xcd_swz(bidl, (int)(gridDim.x * gridDim.y));
  int m0 = (swz / (int)gridDim.x) * 256, n0 = (swz % (int)gridDim.x) * 256;
  f4v acc[8][4] = {};
  s8v afh[2][4][2];  // held A fragments [MH][tm][s]
  s8v bfh[2][2][2];  // held B fragments [NH][tn][s]

  auto stageA = [&](int par, int h, int kt) {
#pragma unroll
    for (int i = 0; i < 2; ++i) {
      int cb = w * 128 + i * 64;
      int ci = cb + lane;
      int r = ci >> 3, c = ci & 7;
      int cs = c ^ (r & 7);
      int grow = ((r >> 6) << 7) + h * 64 + (r & 63);
      async16(A + (size_t)(m0 + grow) * K + kt * 64 + cs * 8,
              &lsA[par][h][cb * 8]);
    }
  };
  auto stageB = [&](int par, int h, int kt) {
#pragma unroll
    for (int i = 0; i < 2; ++i) {
      int cb = w * 128 + i * 64;
      int ci = cb + lane;
      int r = ci >> 3, c = ci & 7;
      int cs = c ^ (r & 7);
      int gn = ((r >> 5) << 6) + h * 32 + (r & 31);
      async16(Bt + (size_t)(n0 + gn) * K + kt * 64 + cs * 8,
              &lsB[par][h][cb * 8]);
    }
  };

#define PHASE(PAR, MH, NH, RA, RB, STAGE_STMT, VMN)                            \
  {                                                                            \
    if (RA) {                                                                  \
      _Pragma("unroll") for (int tm = 0; tm < 4; ++tm) {                       \
        int lr = wr * 64 + tm * 16 + l16;                                      \
        _Pragma("unroll") for (int s = 0; s < 2; ++s) {                        \
          int ac = (s * 4 + quad) ^ (lr & 7);                                  \
          afh[MH][tm][s] = *(const s8v*)(&lsA[PAR][MH][lr * 64 + ac * 8]);     \
        }                                                                      \
      }                                                                        \
    }                                                                          \
    if (RB) {                                                                  \
      _Pragma("unroll") for (int tn = 0; tn < 2; ++tn) {                       \
        int rb = wc * 32 + tn * 16 + l16;                                      \
        _Pragma("unroll") for (int s = 0; s < 2; ++s) {                        \
          int bc = (s * 4 + quad) ^ (rb & 7);                                  \
          bfh[NH][tn][s] = *(const s8v*)(&lsB[PAR][NH][rb * 64 + bc * 8]);     \
        }                                                                      \
      }                                                                        \
    }                                                                          \
    STAGE_STMT;                                                                \
    __builtin_amdgcn_sched_barrier(0);                                         \
    __builtin_amdgcn_s_barrier();                                              \
    __builtin_amdgcn_sched_barrier(0);                                         \
    __builtin_amdgcn_s_setprio(1);                                             \
    _Pragma("unroll") for (int s = 0; s < 2; ++s)                              \
      _Pragma("unroll") for (int tm = 0; tm < 4; ++tm)                         \
        _Pragma("unroll") for (int tn = 0; tn < 2; ++tn)                       \
          acc[MH * 4 + tm][NH * 2 + tn] =                                      \
              __builtin_amdgcn_mfma_f32_16x16x32_bf16(                         \
                  afh[MH][tm][s], bfh[NH][tn][s],                              \
                  acc[MH * 4 + tm][NH * 2 + tn], 0, 0, 0);                     \
    __builtin_amdgcn_s_setprio(0);                                             \
    __builtin_amdgcn_sched_barrier(0);                                         \
    if (VMN == 4) { asm volatile("s_waitcnt vmcnt(4)" ::: "memory"); }         \
    else if (VMN == 0) { asm volatile("s_waitcnt vmcnt(0)" ::: "memory"); }    \
    __builtin_amdgcn_sched_barrier(0);                                         \
    __builtin_amdgcn_s_barrier();                                              \
    __builtin_amdgcn_sched_barrier(0);                                         \
  }

  int nT = K >> 6;  // assumes nT even, >= 4
  stageA(0, 0, 0); stageB(0, 0, 0); stageA(0, 1, 0); stageB(0, 1, 0);
  stageB(1, 0, 1); stageA(1, 0, 1);
  asm volatile("s_waitcnt vmcnt(4)" ::: "memory");
  __builtin_amdgcn_sched_barrier(0);
  __builtin_amdgcn_s_barrier();
  __builtin_amdgcn_sched_barrier(0);

  for (int t = 0; t < nT; t += 2) {
    bool s2 = (t + 2) < nT, s3 = (t + 3) < nT;
    PHASE(0, 0, 0, 1, 1, { stageA(1, 1, t + 1); }, -1)                 // ph1
    PHASE(0, 1, 0, 1, 0, { stageB(1, 1, t + 1); }, -1)                 // ph2
    PHASE(0, 0, 1, 0, 1, { if (s2) stageB(0, 0, t + 2); }, -1)         // ph3
    PHASE(0, 1, 1, 0, 0, { if (s2) stageA(0, 0, t + 2); }, (s2 ? 4 : 0)) // ph4
    PHASE(1, 0, 0, 1, 1, { if (s2) stageA(0, 1, t + 2); }, -1)         // ph5
    PHASE(1, 1, 0, 1, 0, { if (s2) stageB(0, 1, t + 2); }, -1)         // ph6
    PHASE(1, 0, 1, 0, 1, { if (s3) stageB(1, 0, t + 3); }, -1)         // ph7
    PHASE(1, 1, 1, 0, 0, { if (s3) stageA(1, 0, t + 3); }, (s3 ? 4 : 0)) // ph8
  }
#undef PHASE

#pragma unroll
  for (int mi = 0; mi < 8; ++mi) {
    int mh = mi >> 2, tm = mi & 3;
#pragma unroll
    for (int nj = 0; nj < 4; ++nj) {
      int nh = nj >> 1, tn = nj & 1;
      int col = n0 + wc * 64 + nh * 32 + tn * 16 + l16;
      float bv = bias[col];
#pragma unroll
      for (int r = 0; r < 4; ++r) {
        int rowg = m0 + wr * 128 + mh * 64 + tm * 16 + quad * 4 + r;
        float vv = acc[mi][nj][r] + bv;
        if (relu) vv = fmaxf(vv, 0.f);
        out[(size_t)rowg * N + col] = f2b(vv);
      }
    }
  }
}

// ---------------- proj GEMM with fused attention-combine A-staging ----------
__global__ __launch_bounds__(256) void gemm_proj(
    const unsigned short* __restrict__ Opart, const float* __restrict__ lpart,
    const unsigned short* __restrict__ Bt, const float* __restrict__ bias,
    const float* __restrict__ res, float* __restrict__ out, int M, int N, int K) {
  __shared__ __align__(16) unsigned short lsA[2][64 * 64];
  __shared__ __align__(16) unsigned short lsB[2][64 * 64];
  int tid = threadIdx.x;
  int lane = tid & 63, w = tid >> 6, quad = lane >> 4, l16 = lane & 15;
  int bidl = blockIdx.y * (int)gridDim.x + blockIdx.x;
  int swz = xcd_swz(bidl, (int)(gridDim.x * gridDim.y));
  int m0 = (swz / (int)gridDim.x) * 64, n0 = (swz % (int)gridDim.x) * 64;
  int wm = (w >> 1) * 32, wn = (w & 1) * 32;
  f4v acc[2][2] = {};

  int ci_[2], csA[2], mA[2], b2A[2], lA[2];
#pragma unroll
  for (int i = 0; i < 2; ++i) {
    int cb = w * 128 + i * 64;
    int ci = cb + lane;
    int row = ci >> 3, c = ci & 7;
    ci_[i] = ci; csA[i] = c ^ (row & 7);
    mA[i] = m0 + row; b2A[i] = mA[i] >> 11; lA[i] = mA[i] & 2047;
  }
  s8v o0r[2], o1r[2];
  float lsr0[2], lsr1[2];
  auto issueA = [&](int kt) {
#pragma unroll
    for (int i = 0; i < 2; ++i) {
      const unsigned short* pa =
          Opart + (size_t)mA[i] * D_MODEL + kt * 64 + csA[i] * 8;
      o0r[i] = *(const s8v*)pa;
      o1r[i] = *(const s8v*)(pa + (size_t)MROWS * D_MODEL);
      size_t lidx = ((size_t)b2A[i] * NH + kt) * SEQ + lA[i];
      lsr0[i] = lpart[lidx];
      lsr1[i] = lpart[(size_t)BATCH * NH * SEQ + lidx];
    }
  };
  auto issueB = [&](int bsel, int ktE) {
#pragma unroll
    for (int i = 0; i < 2; ++i) {
      int cb = w * 128 + i * 64;
      int ci = cb + lane;
      int row = ci >> 3, c = ci & 7;
      int cs = c ^ (row & 7);
      async16(Bt + (size_t)(n0 + row) * K + ktE + cs * 8, &lsB[bsel][cb * 8]);
    }
  };
  auto combineWrite = [&](int bsel) {
#pragma unroll
    for (int i = 0; i < 2; ++i) {
      float inv = KH_ISCALE / (lsr0[i] + lsr1[i]);
      float f[8];
#pragma unroll
      for (int j = 0; j < 8; ++j)
        f[j] = (b2f((unsigned short)o0r[i][j]) +
                b2f((unsigned short)o1r[i][j])) * inv;
      s4v lo = cvt4(f[0], f[1], f[2], f[3]);
      s4v hi = cvt4(f[4], f[5], f[6], f[7]);
      s8v vv = {lo[0], lo[1], lo[2], lo[3], hi[0], hi[1], hi[2], hi[3]};
      *(s8v*)(&lsA[bsel][ci_[i] * 8]) = vv;
    }
  };

  issueA(0); issueB(0, 0);
  __builtin_amdgcn_sched_barrier(0);
  asm volatile("s_waitcnt vmcnt(2)" ::: "memory");
  __builtin_amdgcn_sched_barrier(0);
  combineWrite(0);
  asm volatile("s_waitcnt lgkmcnt(0)" ::: "memory");
  __builtin_amdgcn_sched_barrier(0);

  int nK = K >> 6;
  for (int kt = 0; kt < nK; ++kt) {
    int b = kt & 1;
    if (kt + 1 < nK) {
      issueA(kt + 1); issueB(b ^ 1, (kt + 1) << 6);
      __builtin_amdgcn_sched_barrier(0);
      asm volatile("s_waitcnt vmcnt(10)" ::: "memory");
    } else {
      __builtin_amdgcn_sched_barrier(0);
      asm volatile("s_waitcnt vmcnt(0)" ::: "memory");
    }
    __builtin_amdgcn_sched_barrier(0);
    __builtin_amdgcn_s_barrier();
    __builtin_amdgcn_sched_barrier(0);
#pragma unroll
    for (int s = 0; s < 2; ++s) {
      s8v af[2], bf[2];
#pragma unroll
      for (int t = 0; t < 2; ++t) {
        int am = wm + t * 16 + l16;
        int ac = (s * 4 + quad) ^ (am & 7);
        af[t] = *(const s8v*)(&lsA[b][am * 64 + ac * 8]);
      }
#pragma unroll
      for (int t = 0; t < 2; ++t) {
        int bn = wn + t * 16 + l16;
        int bc = (s * 4 + quad) ^ (bn & 7);
        bf[t] = *(const s8v*)(&lsB[b][bn * 64 + bc * 8]);
      }
#pragma unroll
      for (int ti = 0; ti < 2; ++ti)
#pragma unroll
        for (int tj = 0; tj < 2; ++tj)
          acc[ti][tj] = __builtin_amdgcn_mfma_f32_16x16x32_bf16(
              af[ti], bf[tj], acc[ti][tj], 0, 0, 0);
    }
    if (kt + 1 < nK) {
      __builtin_amdgcn_sched_barrier(0);
      asm volatile("s_waitcnt vmcnt(2)" ::: "memory");
      __builtin_amdgcn_sched_barrier(0);
      combineWrite(b ^ 1);
    }
    asm volatile("s_waitcnt lgkmcnt(0)" ::: "memory");
    __builtin_amdgcn_sched_barrier(0);
    __builtin_amdgcn_s_barrier();
    __builtin_amdgcn_sched_barrier(0);
  }
#pragma unroll
  for (int tj = 0; tj < 2; ++tj) {
    int col = n0 + wn + tj * 16 + l16;
    float bv = bias[col];
#pragma unroll
    for (int ti = 0; ti < 2; ++ti) {
#pragma unroll
      for (int r = 0; r < 4; ++r) {
        int rowg = m0 + wm + ti * 16 + quad * 4 + r;
        float vv = acc[ti][tj][r] + bv + res[(size_t)rowg * N + col];
        out[(size_t)rowg * N + col] = vv;
      }
    }
  }
}

// ---------------- fused flash attention, tr-read V, register-P, XCD-local ---
__global__ __launch_bounds__(256) void flash_k(
    const unsigned short* __restrict__ kh,
    unsigned short* __restrict__ Opart, float* __restrict__ lpart) {
  __shared__ __align__(16) unsigned short lsK[2][8192];  // 2x16KB subtiled
  int tid = threadIdx.x;
  int lane = tid & 63, w = tid >> 6, quad = lane >> 4, l16 = lane & 15;
  int split = blockIdx.x, bh = blockIdx.y, qb = blockIdx.z;
  const unsigned short* khB = kh + (size_t)bh * SEQ * DH;
  unsigned short* Op = Opart + (size_t)split * MROWS * D_MODEL;
  float* lp = lpart + (size_t)split * BATCH * NH * SEQ;
  s8v aQ[2][2];
#pragma unroll
  for (int g = 0; g < 2; ++g) {
    int q = qb * 128 + w * 32 + g * 16 + l16;
#pragma unroll
    for (int s = 0; s < 2; ++s)
      aQ[g][s] = *(const s8v*)(khB + (size_t)q * DH + s * 32 + quad * 8);
  }
  const s8v vone8 = {(short)0x3F80, (short)0x3F80, (short)0x3F80, (short)0x3F80,
                     (short)0x3F80, (short)0x3F80, (short)0x3F80, (short)0x3F80};
  f4v accO[2][4] = {};
  f4v accL[2] = {};

  auto stageK = [&](int bsel, int key0) {
#pragma unroll
    for (int i = 0; i < 4; ++i) {
      int ci = w * 256 + i * 64 + lane;
      async16(khB + (size_t)(key0 + ((ci >> 1) & 127)) * DH +
                  (ci >> 8) * 16 + (ci & 1) * 8,
              &lsK[bsel][(w * 256 + i * 64) * 8]);
    }
  };
  lds_cp ls0 = (lds_cp)&lsK[0][0];
  lds_cp trb = ls0 + quad * 64 + l16 * 4;  // elements

  stageK(0, split * 1024);
  for (int kt8 = 0; kt8 < 8; ++kt8) {
    int b = kt8 & 1;
    if (kt8 + 1 < 8) {
      stageK(b ^ 1, split * 1024 + (kt8 + 1) * 128);
      asm volatile("s_waitcnt vmcnt(4)" ::: "memory");
    } else {
      asm volatile("s_waitcnt vmcnt(0)" ::: "memory");
    }
    __builtin_amdgcn_sched_barrier(0);
    __builtin_amdgcn_s_barrier();
    __builtin_amdgcn_sched_barrier(0);
#pragma unroll
    for (int half = 0; half < 2; ++half) {
      f4v accST[2][4] = {};
#pragma unroll
      for (int s = 0; s < 2; ++s) {
#pragma unroll
        for (int tj = 0; tj < 4; ++tj) {
          s8v kf = *(const s8v*)(&lsK[b][(2 * s + (quad >> 1)) * 2048 +
                                         (half * 64 + tj * 16 + l16) * 16 +
                                         (quad & 1) * 8]);
#pragma unroll
          for (int g = 0; g < 2; ++g)
            accST[g][tj] = __builtin_amdgcn_mfma_f32_16x16x32_bf16(
                kf, aQ[g][s], accST[g][tj], 0, 0, 0);
        }
      }
      s4v pprev[2];
#pragma unroll
      for (int tj = 0; tj < 4; ++tj) {
        s4v vt[4];
#pragma unroll
        for (int db = 0; db < 4; ++db)
          vt[db] = tr16(trb + b * 8192 + db * 2048 + half * 1024 + tj * 256);
        s4v pf[2];
#pragma unroll
        for (int g = 0; g < 2; ++g) {
          float p0 = xp2(accST[g][tj][0]);
          float p1 = xp2(accST[g][tj][1]);
          float p2 = xp2(accST[g][tj][2]);
          float p3 = xp2(accST[g][tj][3]);
          pf[g] = cvt4(p0, p1, p2, p3);
        }
        if (tj & 1) {
#pragma unroll
          for (int g = 0; g < 2; ++g) {
            s8v pp = {pprev[g][0], pprev[g][1], pprev[g][2], pprev[g][3],
                      pf[g][0], pf[g][1], pf[g][2], pf[g][3]};
            accL[g] = __builtin_amdgcn_mfma_f32_16x16x32_bf16(
                pp, vone8, accL[g], 0, 0, 0);  // B=1: k-position irrelevant
          }
        } else {
#pragma unroll
          for (int g = 0; g < 2; ++g) pprev[g] = pf[g];
        }
        asm volatile("s_waitcnt lgkmcnt(0)" ::: "memory");  // tr reads landed
        __builtin_amdgcn_sched_barrier(0);
#pragma unroll
        for (int db = 0; db < 4; ++db)
#pragma unroll
          for (int g = 0; g < 2; ++g)
            accO[g][db] = mfma16(pf[g], vt[db], accO[g][db]);
      }
    }
    asm volatile("s_waitcnt lgkmcnt(0)" ::: "memory");
    __builtin_amdgcn_sched_barrier(0);
    __builtin_amdgcn_s_barrier();
    __builtin_amdgcn_sched_barrier(0);
  }
  int b = bh >> 4, h = bh & 15;
#pragma unroll
  for (int g = 0; g < 2; ++g) {
    if (l16 == 0) {
#pragma unroll
      for (int r = 0; r < 4; ++r) {
        int q = qb * 128 + w * 32 + g * 16 + quad * 4 + r;
        lp[(size_t)bh * SEQ + q] = accL[g][r];
      }
    }
#pragma unroll
    for (int r = 0; r < 4; ++r) {
      int l = qb * 128 + w * 32 + g * 16 + quad * 4 + r;
#pragma unroll
      for (int db = 0; db < 4; ++db) {
        int d = db * 16 + l16;
        Op[((size_t)(b * SEQ + l)) * D_MODEL + h * DH + d] = f2b(accO[g][db][r]);
      }
    }
  }
}

// ---------------------------------------------------------------------------
extern "C" void kernel_launch(void* const* d_in, const int* in_sizes, int n_in,
                              void* d_out, int out_size, void* d_ws, size_t ws_size,
                              hipStream_t stream) {
  (void)in_sizes; (void)n_in; (void)out_size;
  const float* x      = (const float*)d_in[0];
  const float* w_attn = (const float*)d_in[1];
  const float* b_attn = (const float*)d_in[2];
  const float* w_proj = (const float*)d_in[3];
  const float* b_proj = (const float*)d_in[4];
  const float* ln1_g  = (const float*)d_in[5];
  const float* ln1_b  = (const float*)d_in[6];
  const float* ln2_g  = (const float*)d_in[7];
  const float* ln2_b  = (const float*)d_in[8];
  const float* w_fc1  = (const float*)d_in[9];
  const float* b_fc1  = (const float*)d_in[10];
  const float* w_fc2  = (const float*)d_in[11];
  const float* b_fc2  = (const float*)d_in[12];

  char* ws = (char*)d_ws;
  unsigned short* Opart = (unsigned short*)ws;                         // [0,16M)
  unsigned short* kh    = (unsigned short*)(ws + (size_t)(16u << 20)); // [16,24)
  float*          x1    = (float*)(ws + (size_t)(32u << 20));          // [32,48)
  unsigned short* hbuf  = (unsigned short*)(ws + (size_t)(48u << 20)); // [48,56)
  float*          lpart = (float*)(ws + (size_t)(48u << 20));  // h1 dead by flash
  float* outf = (float*)d_out;
  bool big_ws = ws_size >= ((size_t)72u << 20);

  unsigned short* wTk;
  unsigned short* wTp;
  unsigned short* wTf1;
  unsigned short* wTf2;
  unsigned short* fc1o;
  if (big_ws) {
    wTk  = (unsigned short*)(ws + (size_t)(56u << 20));
    wTp  = wTk;
    wTf1 = wTk;
    wTf2 = (unsigned short*)(ws + (size_t)(64u << 20));
    fc1o = (unsigned short*)ws;                            // [0,32): Op/kh dead
  } else {
    wTk  = (unsigned short*)ws;
    wTp  = (unsigned short*)(ws + (size_t)(24u << 20));    // free (was khT)
    wTf1 = (unsigned short*)ws;
    wTf2 = (unsigned short*)(ws + (size_t)(8u << 20));
    fc1o = kh;                                             // [16,32): chunked 16MB
  }

  dim3 blk(256);
  dim3 blk2(512);
  // 1. h1 = LN1(x)
  hipLaunchKernelGGL(ln_kernel, dim3(MROWS), blk, 0, stream, x, ln1_g, ln1_b, hbuf);
  // 2. wTk = (w_attn[:, 1024:2048])^T
  hipLaunchKernelGGL(transpose_b<float>, dim3(16, 16, 1), blk, 0, stream,
                     w_attn + 1024, wTk, 3 * D_MODEL, D_MODEL, 0LL, 0LL);
  // 3. kh[b,h,l,d] = (h1 @ w_k + b_k) * KH_SCALE  (R17 gemm_bt)
  hipLaunchKernelGGL((gemm_bt<0, false, true, 0, 64, 64>), dim3(16, 64), blk, 0,
                     stream, hbuf, wTk, b_attn + 1024, nullptr, (void*)kh,
                     MROWS, D_MODEL, D_MODEL);
  // 4. flash (tr-read V; khT eliminated) -> bf16 partials + l partials
  hipLaunchKernelGGL(flash_k, dim3(2, 32, SEQ / 128), blk, 0, stream,
                     kh, Opart, lpart);
  // 5. wTp = w_proj^T ; x1 = combine(Opart,lpart) @ w_proj + b + x  (fused)
  hipLaunchKernelGGL(transpose_b<float>, dim3(16, 16, 1), blk, 0, stream,
                     w_proj, wTp, D_MODEL, D_MODEL, 0LL, 0LL);
  hipLaunchKernelGGL(gemm_proj, dim3(16, 64), blk, 0, stream,
                     Opart, lpart, wTp, b_proj, x, x1,
                     MROWS, D_MODEL, D_MODEL);
  // 6. h2 = LN2(x1)
  hipLaunchKernelGGL(ln_kernel, dim3(MROWS), blk, 0, stream, x1, ln2_g, ln2_b, hbuf);
  // 7. wTf1 = w_fc1^T ; wTf2 = w_fc2^T
  hipLaunchKernelGGL(transpose_b<float>, dim3(64, 16, 1), blk, 0, stream,
                     w_fc1, wTf1, 4 * D_MODEL, D_MODEL, 0LL, 0LL);
  hipLaunchKernelGGL(transpose_b<float>, dim3(16, 64, 1), blk, 0, stream,
                     w_fc2, wTf2, D_MODEL, 4 * D_MODEL, 0LL, 0LL);
  // 8/9. FFN: FC1 8-phase 256^2; FC2 interleaved wave-split-K (32 iters)
  if (big_ws) {
    hipLaunchKernelGGL(gemm256, dim3(16, 16), dim3(512), 0, stream,
                       hbuf, wTf1, b_fc1, fc1o, true,
                       MROWS, 4 * D_MODEL, D_MODEL);
    hipLaunchKernelGGL((gemm_bt2i<2, false, false, 1>), dim3(16, 64), blk2, 0,
                       stream, fc1o, wTf2, b_fc2, x1, (void*)outf,
                       MROWS, D_MODEL, 4 * D_MODEL);
  } else {
    for (int c = 0; c < 2; ++c) {
      const unsigned short* h2c = hbuf + (size_t)c * 2048 * D_MODEL;
      const float* x1c = x1 + (size_t)c * 2048 * D_MODEL;
      float* outc = outf + (size_t)c * 2048 * D_MODEL;
      hipLaunchKernelGGL((gemm_bt<0, true, false, 0, 128, 64>), dim3(64, 16), blk, 0,
                         stream, h2c, wTf1, b_fc1, nullptr, (void*)fc1o,
                         2048, 4 * D_MODEL, D_MODEL);
      hipLaunchKernelGGL((gemm_bt2i<2, false, false, 1>), dim3(16, 32), blk2, 0,
                         stream, fc1o, wTf2, b_fc2, x1c, (void*)outc,
                         2048, D_MODEL, 4 * D_MODEL);
    }
  }
}

// Round 13
// 318.945 us; speedup vs baseline: 1.2513x; 1.0129x over previous
//
#include <hip/hip_runtime.h>

// ---------------------------------------------------------------------------
// Transformer block on MI355X. fp32 I/O (per reference), bf16 MFMA internals,
// fp32 accumulation/residuals.
// R22 == R17-exact revert (best-known, 315.2us). Journal: FC2-plateau escape
// attempts all REFUTED: R18 wave-split-K disjoint (FETCH 57->90MB, +10us),
// R19/20 register-B (uncoalesced per-lane B: 16B/64B-sector, 142us),
// R21 wave-split-K interleaved (FETCH 90MB bit-identical to R18 -> excess
// fetch is structural to 512-thr/2-blk convoy-drift, not K-assignment).
// FC2's 64^2 2-phase @4blk/CU is a robust local optimum for N=1024: 8-phase
// needs 256^2 (grid 64 blocks = too few), larger tiles drop occupancy
// (R11/R12), register-B uncoalesced, split-K over-fetches.
// Structure: R17 gemm256 (8-phase 256^2, T3+T4+T5, register-resident
// fragments, 24 b128/K-tile); R15 flash (lsK subtiled [4dblk][128key][16d],
// ds_read_b64_tr_b16 V, dbuf vmcnt(4), accL via paired K=32 MFMA); R13
// fused combine-proj + XCD-chunk swizzle; R11/12 2-phase dbuf 64^2 gemm_bt;
// R10 kexp folded into kh, cvt_pk P, bare v_exp_f32; R9 XCD-local flash grid.
// ws layout (56MB min, 72MB preferred):
//   [0,16M)  Opart | big: fc1o [0,32M) after proj
//   [16,24M) kh    | fallback: fc1o [16,32M)
//   [24,32M) (free; was khT)
//   [32,48M) x1    [48,56M) hbuf + lpart during flash
//   [56,64M) wT1 (big), [64,72M) wT2 (big)
// ---------------------------------------------------------------------------

typedef __attribute__((ext_vector_type(8))) short s8v;  // 8 bf16 raw
typedef __attribute__((ext_vector_type(4))) short s4v;  // 4 bf16 raw
typedef __attribute__((ext_vector_type(4))) float f4v;  // mfma accumulator

#define D_MODEL 1024
#define SEQ 2048
#define BATCH 2
#define NH 16
#define DH 64
#define MROWS (BATCH * SEQ)

#define KH_SCALE 0.42466088f
#define KH_ISCALE 2.3548200f

__device__ __forceinline__ float b2f(unsigned short u) {
  union { unsigned int i; float f; } v; v.i = ((unsigned int)u) << 16; return v.f;
}
__device__ __forceinline__ unsigned short f2b(float f) {
  unsigned int i = __builtin_bit_cast(unsigned int, f);
  unsigned int r = (i + 0x7fffu + ((i >> 16) & 1u)) >> 16;  // RNE
  return (unsigned short)r;
}
// async global->LDS, 16B/lane; dest = wave-uniform base + lane*16 (m104/m108)
__device__ __forceinline__ void async16(const void* g, void* l) {
  __builtin_amdgcn_global_load_lds(
      (const __attribute__((address_space(1))) unsigned int*)g,
      (__attribute__((address_space(3))) unsigned int*)l, 16, 0, 0);
}
__device__ __forceinline__ unsigned short cvt_b(float f) { return f2b(f); }
__device__ __forceinline__ unsigned short cvt_b(unsigned short u) { return u; }

__device__ __forceinline__ float xp2(float x) {
#if __has_builtin(__builtin_amdgcn_exp2f)
  return __builtin_amdgcn_exp2f(x);
#else
  return exp2f(x);
#endif
}

// 4x f32 -> packed bf16 s4v via v_cvt_pk_bf16_f32 (RNE, 2 instructions).
__device__ __forceinline__ s4v cvt4(float a, float b, float c, float d) {
  unsigned int lo, hi;
  asm("v_cvt_pk_bf16_f32 %0, %1, %2" : "=v"(lo) : "v"(a), "v"(b));
  asm("v_cvt_pk_bf16_f32 %0, %1, %2" : "=v"(hi) : "v"(c), "v"(d));
  union { unsigned long long u; s4v v; } u;
  u.u = ((unsigned long long)hi << 32) | (unsigned long long)lo;
  return u.v;
}

#if __has_builtin(__builtin_amdgcn_mfma_f32_16x16x16_bf16)
__device__ __forceinline__ f4v mfma16(s4v a, s4v b, f4v c) {
  return __builtin_amdgcn_mfma_f32_16x16x16_bf16(a, b, c, 0, 0, 0);
}
#elif __has_builtin(__builtin_amdgcn_mfma_f32_16x16x16bf16_1k)
__device__ __forceinline__ f4v mfma16(s4v a, s4v b, f4v c) {
  return __builtin_amdgcn_mfma_f32_16x16x16bf16_1k(a, b, c, 0, 0, 0);
}
#else
__device__ __forceinline__ f4v mfma16(s4v a, s4v b, f4v c) {
  s8v aa = {a[0], a[1], a[2], a[3], 0, 0, 0, 0};
  s8v bb = {b[0], b[1], b[2], b[3], 0, 0, 0, 0};
  return __builtin_amdgcn_mfma_f32_16x16x32_bf16(aa, bb, c, 0, 0, 0);
}
#endif

// LDS transpose-read: supply the natural per-lane ds_read_b64 address
// (base + lane*8B); each 16-lane group's 128B region is delivered
// column-major: lane l gets column (l&15) of its 4x16 bf16 tile (m156/m162).
typedef __attribute__((address_space(3))) const unsigned short* lds_cp;
__device__ __forceinline__ s4v tr16(lds_cp p) {
  unsigned long long d;
  asm volatile("ds_read_b64_tr_b16 %0, %1" : "=v"(d) : "v"(p));
  return __builtin_bit_cast(s4v, d);
}

// XCD-chunked logical block id (T1); bijective only when nwg%8==0.
__device__ __forceinline__ int xcd_swz(int bidl, int nwg) {
  return (nwg & 7) ? bidl : ((bidl & 7) * (nwg >> 3) + (bidl >> 3));
}

// ---------------- LayerNorm: fp32 in -> bf16 out, one block per row ---------
__global__ __launch_bounds__(256) void ln_kernel(
    const float* __restrict__ x, const float* __restrict__ g,
    const float* __restrict__ bb, unsigned short* __restrict__ out) {
  int row = blockIdx.x;
  int t = threadIdx.x;
  const float* xr = x + (size_t)row * D_MODEL;
  float v[4];
  float s = 0.f, s2 = 0.f;
#pragma unroll
  for (int i = 0; i < 4; ++i) {
    float f = xr[t + 256 * i];
    v[i] = f; s += f; s2 += f * f;
  }
#pragma unroll
  for (int off = 1; off < 64; off <<= 1) {
    s += __shfl_xor(s, off, 64);
    s2 += __shfl_xor(s2, off, 64);
  }
  __shared__ float red[8];
  if ((t & 63) == 0) { red[t >> 6] = s; red[4 + (t >> 6)] = s2; }
  __syncthreads();
  s = red[0] + red[1] + red[2] + red[3];
  s2 = red[4] + red[5] + red[6] + red[7];
  float mu = s * (1.f / D_MODEL);
  float var = s2 * (1.f / D_MODEL) - mu * mu;
  float rstd = rsqrtf(var + 1e-5f);
#pragma unroll
  for (int i = 0; i < 4; ++i) {
    int c = t + 256 * i;
    float h = (v[i] - mu) * rstd * g[c] + bb[c];
    out[(size_t)row * D_MODEL + c] = f2b(h);
  }
}

// ---------------- batched 64x64 tile transpose -> bf16 ----------------------
template <typename T>
__global__ __launch_bounds__(256) void transpose_b(
    const T* __restrict__ src, unsigned short* __restrict__ dst,
    int srcStride, int dstStride, long long srcBatch, long long dstBatch) {
  __shared__ unsigned short tile[64][65];
  const T* s = src + (size_t)blockIdx.z * srcBatch;
  unsigned short* d = dst + (size_t)blockIdx.z * dstBatch;
  int n0 = blockIdx.x * 64, k0 = blockIdx.y * 64;
  for (int i = threadIdx.x; i < 4096; i += 256) {
    int k = i >> 6, n = i & 63;
    tile[k][n] = cvt_b(s[(size_t)(k0 + k) * srcStride + n0 + n]);
  }
  __syncthreads();
  for (int i = threadIdx.x; i < 4096; i += 256) {
    int n = i >> 6, k = i & 63;
    d[(size_t)(n0 + n) * dstStride + k0 + k] = tile[k][n];
  }
}

// ---------------- GEMM: C[M,N] = A[M,K] @ Bt[N,K]^T + bias (+res)(+relu) ----
// BMxBN tile, BK=64, 4 waves (2x2); 2-phase dbuf, counted vmcnt, raw barrier.
template <int RES, bool RELU, bool KH, int OUTF, int BM, int BN>
__global__ __launch_bounds__(256) void gemm_bt(
    const unsigned short* __restrict__ A, const unsigned short* __restrict__ Bt,
    const float* __restrict__ bias, const float* __restrict__ res,
    void* __restrict__ out, int M, int N, int K) {
  constexpr int MT = BM / 32;
  constexpr int NT = BN / 32;
  __shared__ __align__(16) unsigned short lsA[2][BM * 64];
  __shared__ __align__(16) unsigned short lsB[2][BN * 64];
  int tid = threadIdx.x;
  int lane = tid & 63, w = tid >> 6, quad = lane >> 4, l16 = lane & 15;
  int bidl = blockIdx.y * (int)gridDim.x + blockIdx.x;
  int swz = xcd_swz(bidl, (int)(gridDim.x * gridDim.y));
  int m0 = (swz / (int)gridDim.x) * BM, n0 = (swz % (int)gridDim.x) * BN;
  int wm = (w >> 1) * (BM / 2), wn = (w & 1) * (BN / 2);
  f4v acc[MT][NT] = {};

  auto stage = [&](int bsel, int ktE) {
#pragma unroll
    for (int i = 0; i < MT; ++i) {
      int cb = w * (BM * 2) + i * 64;
      int ci = cb + lane;
      int row = ci >> 3, c = ci & 7;
      int cs = c ^ (row & 7);
      async16(A + (size_t)(m0 + row) * K + ktE + cs * 8, &lsA[bsel][cb * 8]);
    }
#pragma unroll
    for (int i = 0; i < NT; ++i) {
      int cb = w * (BN * 2) + i * 64;
      int ci = cb + lane;
      int row = ci >> 3, c = ci & 7;
      int cs = c ^ (row & 7);
      async16(Bt + (size_t)(n0 + row) * K + ktE + cs * 8, &lsB[bsel][cb * 8]);
    }
  };

  stage(0, 0);
  int nK = K >> 6;
  for (int kt = 0; kt < nK; ++kt) {
    int b = kt & 1;
    if (kt + 1 < nK) {
      stage(b ^ 1, (kt + 1) << 6);
      if constexpr (MT + NT == 4)      asm volatile("s_waitcnt vmcnt(4)" ::: "memory");
      else if constexpr (MT + NT == 6) asm volatile("s_waitcnt vmcnt(6)" ::: "memory");
      else                             asm volatile("s_waitcnt vmcnt(8)" ::: "memory");
    } else {
      asm volatile("s_waitcnt vmcnt(0)" ::: "memory");
    }
    __builtin_amdgcn_sched_barrier(0);
    __builtin_amdgcn_s_barrier();
    __builtin_amdgcn_sched_barrier(0);
#pragma unroll
    for (int s = 0; s < 2; ++s) {
      s8v af[MT], bf[NT];
#pragma unroll
      for (int t = 0; t < MT; ++t) {
        int am = wm + t * 16 + l16;
        int ac = (s * 4 + quad) ^ (am & 7);
        af[t] = *(const s8v*)(&lsA[b][am * 64 + ac * 8]);
      }
#pragma unroll
      for (int t = 0; t < NT; ++t) {
        int bn = wn + t * 16 + l16;
        int bc = (s * 4 + quad) ^ (bn & 7);
        bf[t] = *(const s8v*)(&lsB[b][bn * 64 + bc * 8]);
      }
#pragma unroll
      for (int ti = 0; ti < MT; ++ti)
#pragma unroll
        for (int tj = 0; tj < NT; ++tj)
          acc[ti][tj] = __builtin_amdgcn_mfma_f32_16x16x32_bf16(
              af[ti], bf[tj], acc[ti][tj], 0, 0, 0);
    }
    asm volatile("s_waitcnt lgkmcnt(0)" ::: "memory");
    __builtin_amdgcn_sched_barrier(0);
    __builtin_amdgcn_s_barrier();
    __builtin_amdgcn_sched_barrier(0);
  }
#pragma unroll
  for (int tj = 0; tj < NT; ++tj) {
    int col = n0 + wn + tj * 16 + l16;
    float bv = bias[col];
#pragma unroll
    for (int ti = 0; ti < MT; ++ti) {
#pragma unroll
      for (int r = 0; r < 4; ++r) {
        int rowg = m0 + wm + ti * 16 + quad * 4 + r;
        float vv = acc[ti][tj][r] + bv;
        if (KH) vv *= KH_SCALE;
        if (RES == 2) vv += res[(size_t)rowg * N + col];
        if (RELU) vv = fmaxf(vv, 0.f);
        size_t oidx;
        if (KH) {
          int b2 = rowg >> 11, l = rowg & 2047, h = col >> 6, d = col & 63;
          oidx = (((size_t)(b2 * NH + h)) * SEQ + l) * DH + d;
        } else {
          oidx = (size_t)rowg * N + col;
        }
        if (OUTF == 0) ((unsigned short*)out)[oidx] = f2b(vv);
        else           ((float*)out)[oidx] = vv;
      }
    }
  }
}

// ---------------- 256x256 8-phase GEMM (T3+T4+T5), bf16 out + bias (+relu) --
// R17: fragments register-resident across reusing phases. af[MH] read at
// MH's first phase (ph1/ph2), bf[NH] at NH's first phase (ph1/ph3); ph4/ph8
// read nothing. 24 ds_read_b128 per K-tile (was 48).
__global__ __launch_bounds__(512, 2) void gemm256(
    const unsigned short* __restrict__ A, const unsigned short* __restrict__ Bt,
    const float* __restrict__ bias, unsigned short* __restrict__ out,
    bool relu, int M, int N, int K) {
  __shared__ __align__(16) unsigned short lsA[2][2][128 * 64];
  __shared__ __align__(16) unsigned short lsB[2][2][128 * 64];
  int tid = threadIdx.x;
  int lane = tid & 63, w = tid >> 6, quad = lane >> 4, l16 = lane & 15;
  int wr = w >> 2, wc = w & 3;
  int bidl = blockIdx.y * (int)gridDim.x + blockIdx.x;
  int swz = xcd_swz(bidl, (int)(gridDim.x * gridDim.y));
  int m0 = (swz / (int)gridDim.x) * 256, n0 = (swz % (int)gridDim.x) * 256;
  f4v acc[8][4] = {};
  s8v afh[2][4][2];  // held A fragments [MH][tm][s]
  s8v bfh[2][2][2];  // held B fragments [NH][tn][s]

  auto stageA = [&](int par, int h, int kt) {
#pragma unroll
    for (int i = 0; i < 2; ++i) {
      int cb = w * 128 + i * 64;
      int ci = cb + lane;
      int r = ci >> 3, c = ci & 7;
      int cs = c ^ (r & 7);
      int grow = ((r >> 6) << 7) + h * 64 + (r & 63);
      async16(A + (size_t)(m0 + grow) * K + kt * 64 + cs * 8,
              &lsA[par][h][cb * 8]);
    }
  };
  auto stageB = [&](int par, int h, int kt) {
#pragma unroll
    for (int i = 0; i < 2; ++i) {
      int cb = w * 128 + i * 64;
      int ci = cb + lane;
      int r = ci >> 3, c = ci & 7;
      int cs = c ^ (r & 7);
      int gn = ((r >> 5) << 6) + h * 32 + (r & 31);
      async16(Bt + (size_t)(n0 + gn) * K + kt * 64 + cs * 8,
              &lsB[par][h][cb * 8]);
    }
  };

#define PHASE(PAR, MH, NH, RA, RB, STAGE_STMT, VMN)                            \
  {                                                                            \
    if (RA) {                                                                  \
      _Pragma("unroll") for (int tm = 0; tm < 4; ++tm) {                       \
        int lr = wr * 64 + tm * 16 + l16;                                      \
        _Pragma("unroll") for (int s = 0; s < 2; ++s) {                        \
          int ac = (s * 4 + quad) ^ (lr & 7);                                  \
          afh[MH][tm][s] = *(const s8v*)(&lsA[PAR][MH][lr * 64 + ac * 8]);     \
        }                                                                      \
      }                                                                        \
    }                                                                          \
    if (RB) {                                                                  \
      _Pragma("unroll") for (int tn = 0; tn < 2; ++tn) {                       \
        int rb = wc * 32 + tn * 16 + l16;                                      \
        _Pragma("unroll") for (int s = 0; s < 2; ++s) {                        \
          int bc = (s * 4 + quad) ^ (rb & 7);                                  \
          bfh[NH][tn][s] = *(const s8v*)(&lsB[PAR][NH][rb * 64 + bc * 8]);     \
        }                                                                      \
      }                                                                        \
    }                                                                          \
    STAGE_STMT;                                                                \
    __builtin_amdgcn_sched_barrier(0);                                         \
    __builtin_amdgcn_s_barrier();                                              \
    __builtin_amdgcn_sched_barrier(0);                                         \
    __builtin_amdgcn_s_setprio(1);                                             \
    _Pragma("unroll") for (int s = 0; s < 2; ++s)                              \
      _Pragma("unroll") for (int tm = 0; tm < 4; ++tm)                         \
        _Pragma("unroll") for (int tn = 0; tn < 2; ++tn)                       \
          acc[MH * 4 + tm][NH * 2 + tn] =                                      \
              __builtin_amdgcn_mfma_f32_16x16x32_bf16(                         \
                  afh[MH][tm][s], bfh[NH][tn][s],                              \
                  acc[MH * 4 + tm][NH * 2 + tn], 0, 0, 0);                     \
    __builtin_amdgcn_s_setprio(0);                                             \
    __builtin_amdgcn_sched_barrier(0);                                         \
    if (VMN == 4) { asm volatile("s_waitcnt vmcnt(4)" ::: "memory"); }         \
    else if (VMN == 0) { asm volatile("s_waitcnt vmcnt(0)" ::: "memory"); }    \
    __builtin_amdgcn_sched_barrier(0);                                         \
    __builtin_amdgcn_s_barrier();                                              \
    __builtin_amdgcn_sched_barrier(0);                                         \
  }

  int nT = K >> 6;  // assumes nT even, >= 4
  stageA(0, 0, 0); stageB(0, 0, 0); stageA(0, 1, 0); stageB(0, 1, 0);
  stageB(1, 0, 1); stageA(1, 0, 1);
  asm volatile("s_waitcnt vmcnt(4)" ::: "memory");
  __builtin_amdgcn_sched_barrier(0);
  __builtin_amdgcn_s_barrier();
  __builtin_amdgcn_sched_barrier(0);

  for (int t = 0; t < nT; t += 2) {
    bool s2 = (t + 2) < nT, s3 = (t + 3) < nT;
    PHASE(0, 0, 0, 1, 1, { stageA(1, 1, t + 1); }, -1)                 // ph1
    PHASE(0, 1, 0, 1, 0, { stageB(1, 1, t + 1); }, -1)                 // ph2
    PHASE(0, 0, 1, 0, 1, { if (s2) stageB(0, 0, t + 2); }, -1)         // ph3
    PHASE(0, 1, 1, 0, 0, { if (s2) stageA(0, 0, t + 2); }, (s2 ? 4 : 0)) // ph4
    PHASE(1, 0, 0, 1, 1, { if (s2) stageA(0, 1, t + 2); }, -1)         // ph5
    PHASE(1, 1, 0, 1, 0, { if (s2) stageB(0, 1, t + 2); }, -1)         // ph6
    PHASE(1, 0, 1, 0, 1, { if (s3) stageB(1, 0, t + 3); }, -1)         // ph7
    PHASE(1, 1, 1, 0, 0, { if (s3) stageA(1, 0, t + 3); }, (s3 ? 4 : 0)) // ph8
  }
#undef PHASE

#pragma unroll
  for (int mi = 0; mi < 8; ++mi) {
    int mh = mi >> 2, tm = mi & 3;
#pragma unroll
    for (int nj = 0; nj < 4; ++nj) {
      int nh = nj >> 1, tn = nj & 1;
      int col = n0 + wc * 64 + nh * 32 + tn * 16 + l16;
      float bv = bias[col];
#pragma unroll
      for (int r = 0; r < 4; ++r) {
        int rowg = m0 + wr * 128 + mh * 64 + tm * 16 + quad * 4 + r;
        float vv = acc[mi][nj][r] + bv;
        if (relu) vv = fmaxf(vv, 0.f);
        out[(size_t)rowg * N + col] = f2b(vv);
      }
    }
  }
}

// ---------------- proj GEMM with fused attention-combine A-staging ----------
__global__ __launch_bounds__(256) void gemm_proj(
    const unsigned short* __restrict__ Opart, const float* __restrict__ lpart,
    const unsigned short* __restrict__ Bt, const float* __restrict__ bias,
    const float* __restrict__ res, float* __restrict__ out, int M, int N, int K) {
  __shared__ __align__(16) unsigned short lsA[2][64 * 64];
  __shared__ __align__(16) unsigned short lsB[2][64 * 64];
  int tid = threadIdx.x;
  int lane = tid & 63, w = tid >> 6, quad = lane >> 4, l16 = lane & 15;
  int bidl = blockIdx.y * (int)gridDim.x + blockIdx.x;
  int swz = xcd_swz(bidl, (int)(gridDim.x * gridDim.y));
  int m0 = (swz / (int)gridDim.x) * 64, n0 = (swz % (int)gridDim.x) * 64;
  int wm = (w >> 1) * 32, wn = (w & 1) * 32;
  f4v acc[2][2] = {};

  int ci_[2], csA[2], mA[2], b2A[2], lA[2];
#pragma unroll
  for (int i = 0; i < 2; ++i) {
    int cb = w * 128 + i * 64;
    int ci = cb + lane;
    int row = ci >> 3, c = ci & 7;
    ci_[i] = ci; csA[i] = c ^ (row & 7);
    mA[i] = m0 + row; b2A[i] = mA[i] >> 11; lA[i] = mA[i] & 2047;
  }
  s8v o0r[2], o1r[2];
  float lsr0[2], lsr1[2];
  auto issueA = [&](int kt) {
#pragma unroll
    for (int i = 0; i < 2; ++i) {
      const unsigned short* pa =
          Opart + (size_t)mA[i] * D_MODEL + kt * 64 + csA[i] * 8;
      o0r[i] = *(const s8v*)pa;
      o1r[i] = *(const s8v*)(pa + (size_t)MROWS * D_MODEL);
      size_t lidx = ((size_t)b2A[i] * NH + kt) * SEQ + lA[i];
      lsr0[i] = lpart[lidx];
      lsr1[i] = lpart[(size_t)BATCH * NH * SEQ + lidx];
    }
  };
  auto issueB = [&](int bsel, int ktE) {
#pragma unroll
    for (int i = 0; i < 2; ++i) {
      int cb = w * 128 + i * 64;
      int ci = cb + lane;
      int row = ci >> 3, c = ci & 7;
      int cs = c ^ (row & 7);
      async16(Bt + (size_t)(n0 + row) * K + ktE + cs * 8, &lsB[bsel][cb * 8]);
    }
  };
  auto combineWrite = [&](int bsel) {
#pragma unroll
    for (int i = 0; i < 2; ++i) {
      float inv = KH_ISCALE / (lsr0[i] + lsr1[i]);
      float f[8];
#pragma unroll
      for (int j = 0; j < 8; ++j)
        f[j] = (b2f((unsigned short)o0r[i][j]) +
                b2f((unsigned short)o1r[i][j])) * inv;
      s4v lo = cvt4(f[0], f[1], f[2], f[3]);
      s4v hi = cvt4(f[4], f[5], f[6], f[7]);
      s8v vv = {lo[0], lo[1], lo[2], lo[3], hi[0], hi[1], hi[2], hi[3]};
      *(s8v*)(&lsA[bsel][ci_[i] * 8]) = vv;
    }
  };

  issueA(0); issueB(0, 0);
  __builtin_amdgcn_sched_barrier(0);
  asm volatile("s_waitcnt vmcnt(2)" ::: "memory");
  __builtin_amdgcn_sched_barrier(0);
  combineWrite(0);
  asm volatile("s_waitcnt lgkmcnt(0)" ::: "memory");
  __builtin_amdgcn_sched_barrier(0);

  int nK = K >> 6;
  for (int kt = 0; kt < nK; ++kt) {
    int b = kt & 1;
    if (kt + 1 < nK) {
      issueA(kt + 1); issueB(b ^ 1, (kt + 1) << 6);
      __builtin_amdgcn_sched_barrier(0);
      asm volatile("s_waitcnt vmcnt(10)" ::: "memory");
    } else {
      __builtin_amdgcn_sched_barrier(0);
      asm volatile("s_waitcnt vmcnt(0)" ::: "memory");
    }
    __builtin_amdgcn_sched_barrier(0);
    __builtin_amdgcn_s_barrier();
    __builtin_amdgcn_sched_barrier(0);
#pragma unroll
    for (int s = 0; s < 2; ++s) {
      s8v af[2], bf[2];
#pragma unroll
      for (int t = 0; t < 2; ++t) {
        int am = wm + t * 16 + l16;
        int ac = (s * 4 + quad) ^ (am & 7);
        af[t] = *(const s8v*)(&lsA[b][am * 64 + ac * 8]);
      }
#pragma unroll
      for (int t = 0; t < 2; ++t) {
        int bn = wn + t * 16 + l16;
        int bc = (s * 4 + quad) ^ (bn & 7);
        bf[t] = *(const s8v*)(&lsB[b][bn * 64 + bc * 8]);
      }
#pragma unroll
      for (int ti = 0; ti < 2; ++ti)
#pragma unroll
        for (int tj = 0; tj < 2; ++tj)
          acc[ti][tj] = __builtin_amdgcn_mfma_f32_16x16x32_bf16(
              af[ti], bf[tj], acc[ti][tj], 0, 0, 0);
    }
    if (kt + 1 < nK) {
      __builtin_amdgcn_sched_barrier(0);
      asm volatile("s_waitcnt vmcnt(2)" ::: "memory");
      __builtin_amdgcn_sched_barrier(0);
      combineWrite(b ^ 1);
    }
    asm volatile("s_waitcnt lgkmcnt(0)" ::: "memory");
    __builtin_amdgcn_sched_barrier(0);
    __builtin_amdgcn_s_barrier();
    __builtin_amdgcn_sched_barrier(0);
  }
#pragma unroll
  for (int tj = 0; tj < 2; ++tj) {
    int col = n0 + wn + tj * 16 + l16;
    float bv = bias[col];
#pragma unroll
    for (int ti = 0; ti < 2; ++ti) {
#pragma unroll
      for (int r = 0; r < 4; ++r) {
        int rowg = m0 + wm + ti * 16 + quad * 4 + r;
        float vv = acc[ti][tj][r] + bv + res[(size_t)rowg * N + col];
        out[(size_t)rowg * N + col] = vv;
      }
    }
  }
}

// ---------------- fused flash attention, tr-read V, register-P, XCD-local ---
__global__ __launch_bounds__(256) void flash_k(
    const unsigned short* __restrict__ kh,
    unsigned short* __restrict__ Opart, float* __restrict__ lpart) {
  __shared__ __align__(16) unsigned short lsK[2][8192];  // 2x16KB subtiled
  int tid = threadIdx.x;
  int lane = tid & 63, w = tid >> 6, quad = lane >> 4, l16 = lane & 15;
  int split = blockIdx.x, bh = blockIdx.y, qb = blockIdx.z;
  const unsigned short* khB = kh + (size_t)bh * SEQ * DH;
  unsigned short* Op = Opart + (size_t)split * MROWS * D_MODEL;
  float* lp = lpart + (size_t)split * BATCH * NH * SEQ;
  s8v aQ[2][2];
#pragma unroll
  for (int g = 0; g < 2; ++g) {
    int q = qb * 128 + w * 32 + g * 16 + l16;
#pragma unroll
    for (int s = 0; s < 2; ++s)
      aQ[g][s] = *(const s8v*)(khB + (size_t)q * DH + s * 32 + quad * 8);
  }
  const s8v vone8 = {(short)0x3F80, (short)0x3F80, (short)0x3F80, (short)0x3F80,
                     (short)0x3F80, (short)0x3F80, (short)0x3F80, (short)0x3F80};
  f4v accO[2][4] = {};
  f4v accL[2] = {};

  auto stageK = [&](int bsel, int key0) {
#pragma unroll
    for (int i = 0; i < 4; ++i) {
      int ci = w * 256 + i * 64 + lane;
      async16(khB + (size_t)(key0 + ((ci >> 1) & 127)) * DH +
                  (ci >> 8) * 16 + (ci & 1) * 8,
              &lsK[bsel][(w * 256 + i * 64) * 8]);
    }
  };
  lds_cp ls0 = (lds_cp)&lsK[0][0];
  lds_cp trb = ls0 + quad * 64 + l16 * 4;  // elements

  stageK(0, split * 1024);
  for (int kt8 = 0; kt8 < 8; ++kt8) {
    int b = kt8 & 1;
    if (kt8 + 1 < 8) {
      stageK(b ^ 1, split * 1024 + (kt8 + 1) * 128);
      asm volatile("s_waitcnt vmcnt(4)" ::: "memory");
    } else {
      asm volatile("s_waitcnt vmcnt(0)" ::: "memory");
    }
    __builtin_amdgcn_sched_barrier(0);
    __builtin_amdgcn_s_barrier();
    __builtin_amdgcn_sched_barrier(0);
#pragma unroll
    for (int half = 0; half < 2; ++half) {
      f4v accST[2][4] = {};
#pragma unroll
      for (int s = 0; s < 2; ++s) {
#pragma unroll
        for (int tj = 0; tj < 4; ++tj) {
          s8v kf = *(const s8v*)(&lsK[b][(2 * s + (quad >> 1)) * 2048 +
                                         (half * 64 + tj * 16 + l16) * 16 +
                                         (quad & 1) * 8]);
#pragma unroll
          for (int g = 0; g < 2; ++g)
            accST[g][tj] = __builtin_amdgcn_mfma_f32_16x16x32_bf16(
                kf, aQ[g][s], accST[g][tj], 0, 0, 0);
        }
      }
      s4v pprev[2];
#pragma unroll
      for (int tj = 0; tj < 4; ++tj) {
        s4v vt[4];
#pragma unroll
        for (int db = 0; db < 4; ++db)
          vt[db] = tr16(trb + b * 8192 + db * 2048 + half * 1024 + tj * 256);
        s4v pf[2];
#pragma unroll
        for (int g = 0; g < 2; ++g) {
          float p0 = xp2(accST[g][tj][0]);
          float p1 = xp2(accST[g][tj][1]);
          float p2 = xp2(accST[g][tj][2]);
          float p3 = xp2(accST[g][tj][3]);
          pf[g] = cvt4(p0, p1, p2, p3);
        }
        if (tj & 1) {
#pragma unroll
          for (int g = 0; g < 2; ++g) {
            s8v pp = {pprev[g][0], pprev[g][1], pprev[g][2], pprev[g][3],
                      pf[g][0], pf[g][1], pf[g][2], pf[g][3]};
            accL[g] = __builtin_amdgcn_mfma_f32_16x16x32_bf16(
                pp, vone8, accL[g], 0, 0, 0);  // B=1: k-position irrelevant
          }
        } else {
#pragma unroll
          for (int g = 0; g < 2; ++g) pprev[g] = pf[g];
        }
        asm volatile("s_waitcnt lgkmcnt(0)" ::: "memory");  // tr reads landed
        __builtin_amdgcn_sched_barrier(0);
#pragma unroll
        for (int db = 0; db < 4; ++db)
#pragma unroll
          for (int g = 0; g < 2; ++g)
            accO[g][db] = mfma16(pf[g], vt[db], accO[g][db]);
      }
    }
    asm volatile("s_waitcnt lgkmcnt(0)" ::: "memory");
    __builtin_amdgcn_sched_barrier(0);
    __builtin_amdgcn_s_barrier();
    __builtin_amdgcn_sched_barrier(0);
  }
  int b = bh >> 4, h = bh & 15;
#pragma unroll
  for (int g = 0; g < 2; ++g) {
    if (l16 == 0) {
#pragma unroll
      for (int r = 0; r < 4; ++r) {
        int q = qb * 128 + w * 32 + g * 16 + quad * 4 + r;
        lp[(size_t)bh * SEQ + q] = accL[g][r];
      }
    }
#pragma unroll
    for (int r = 0; r < 4; ++r) {
      int l = qb * 128 + w * 32 + g * 16 + quad * 4 + r;
#pragma unroll
      for (int db = 0; db < 4; ++db) {
        int d = db * 16 + l16;
        Op[((size_t)(b * SEQ + l)) * D_MODEL + h * DH + d] = f2b(accO[g][db][r]);
      }
    }
  }
}

// ---------------------------------------------------------------------------
extern "C" void kernel_launch(void* const* d_in, const int* in_sizes, int n_in,
                              void* d_out, int out_size, void* d_ws, size_t ws_size,
                              hipStream_t stream) {
  (void)in_sizes; (void)n_in; (void)out_size;
  const float* x      = (const float*)d_in[0];
  const float* w_attn = (const float*)d_in[1];
  const float* b_attn = (const float*)d_in[2];
  const float* w_proj = (const float*)d_in[3];
  const float* b_proj = (const float*)d_in[4];
  const float* ln1_g  = (const float*)d_in[5];
  const float* ln1_b  = (const float*)d_in[6];
  const float* ln2_g  = (const float*)d_in[7];
  const float* ln2_b  = (const float*)d_in[8];
  const float* w_fc1  = (const float*)d_in[9];
  const float* b_fc1  = (const float*)d_in[10];
  const float* w_fc2  = (const float*)d_in[11];
  const float* b_fc2  = (const float*)d_in[12];

  char* ws = (char*)d_ws;
  unsigned short* Opart = (unsigned short*)ws;                         // [0,16M)
  unsigned short* kh    = (unsigned short*)(ws + (size_t)(16u << 20)); // [16,24)
  float*          x1    = (float*)(ws + (size_t)(32u << 20));          // [32,48)
  unsigned short* hbuf  = (unsigned short*)(ws + (size_t)(48u << 20)); // [48,56)
  float*          lpart = (float*)(ws + (size_t)(48u << 20));  // h1 dead by flash
  float* outf = (float*)d_out;
  bool big_ws = ws_size >= ((size_t)72u << 20);

  unsigned short* wTk;
  unsigned short* wTp;
  unsigned short* wTf1;
  unsigned short* wTf2;
  unsigned short* fc1o;
  if (big_ws) {
    wTk  = (unsigned short*)(ws + (size_t)(56u << 20));
    wTp  = wTk;
    wTf1 = wTk;
    wTf2 = (unsigned short*)(ws + (size_t)(64u << 20));
    fc1o = (unsigned short*)ws;                            // [0,32): Op/kh dead
  } else {
    wTk  = (unsigned short*)ws;
    wTp  = (unsigned short*)(ws + (size_t)(24u << 20));    // free (was khT)
    wTf1 = (unsigned short*)ws;
    wTf2 = (unsigned short*)(ws + (size_t)(8u << 20));
    fc1o = kh;                                             // [16,32): chunked 16MB
  }

  dim3 blk(256);
  // 1. h1 = LN1(x)
  hipLaunchKernelGGL(ln_kernel, dim3(MROWS), blk, 0, stream, x, ln1_g, ln1_b, hbuf);
  // 2. wTk = (w_attn[:, 1024:2048])^T
  hipLaunchKernelGGL(transpose_b<float>, dim3(16, 16, 1), blk, 0, stream,
                     w_attn + 1024, wTk, 3 * D_MODEL, D_MODEL, 0LL, 0LL);
  // 3. kh[b,h,l,d] = (h1 @ w_k + b_k) * KH_SCALE
  hipLaunchKernelGGL((gemm_bt<0, false, true, 0, 64, 64>), dim3(16, 64), blk, 0,
                     stream, hbuf, wTk, b_attn + 1024, nullptr, (void*)kh,
                     MROWS, D_MODEL, D_MODEL);
  // 4. flash (tr-read V; khT eliminated) -> bf16 partials + l partials
  hipLaunchKernelGGL(flash_k, dim3(2, 32, SEQ / 128), blk, 0, stream,
                     kh, Opart, lpart);
  // 5. wTp = w_proj^T ; x1 = combine(Opart,lpart) @ w_proj + b + x  (fused)
  hipLaunchKernelGGL(transpose_b<float>, dim3(16, 16, 1), blk, 0, stream,
                     w_proj, wTp, D_MODEL, D_MODEL, 0LL, 0LL);
  hipLaunchKernelGGL(gemm_proj, dim3(16, 64), blk, 0, stream,
                     Opart, lpart, wTp, b_proj, x, x1,
                     MROWS, D_MODEL, D_MODEL);
  // 6. h2 = LN2(x1)
  hipLaunchKernelGGL(ln_kernel, dim3(MROWS), blk, 0, stream, x1, ln2_g, ln2_b, hbuf);
  // 7. wTf1 = w_fc1^T ; wTf2 = w_fc2^T
  hipLaunchKernelGGL(transpose_b<float>, dim3(64, 16, 1), blk, 0, stream,
                     w_fc1, wTf1, 4 * D_MODEL, D_MODEL, 0LL, 0LL);
  hipLaunchKernelGGL(transpose_b<float>, dim3(16, 64, 1), blk, 0, stream,
                     w_fc2, wTf2, D_MODEL, 4 * D_MODEL, 0LL, 0LL);
  // 8/9. FFN: FC1 8-phase 256^2 (256 blocks = 1/CU); FC2 BM=64 (1024 blocks)
  if (big_ws) {
    hipLaunchKernelGGL(gemm256, dim3(16, 16), dim3(512), 0, stream,
                       hbuf, wTf1, b_fc1, fc1o, true,
                       MROWS, 4 * D_MODEL, D_MODEL);
    hipLaunchKernelGGL((gemm_bt<2, false, false, 1, 64, 64>), dim3(16, 64), blk, 0,
                       stream, fc1o, wTf2, b_fc2, x1, (void*)outf,
                       MROWS, D_MODEL, 4 * D_MODEL);
  } else {
    for (int c = 0; c < 2; ++c) {
      const unsigned short* h2c = hbuf + (size_t)c * 2048 * D_MODEL;
      const float* x1c = x1 + (size_t)c * 2048 * D_MODEL;
      float* outc = outf + (size_t)c * 2048 * D_MODEL;
      hipLaunchKernelGGL((gemm_bt<0, true, false, 0, 128, 64>), dim3(64, 16), blk, 0,
                         stream, h2c, wTf1, b_fc1, nullptr, (void*)fc1o,
                         2048, 4 * D_MODEL, D_MODEL);
      hipLaunchKernelGGL((gemm_bt<2, false, false, 1, 64, 64>), dim3(16, 32), blk, 0,
                         stream, fc1o, wTf2, b_fc2, x1c, (void*)outc,
                         2048, D_MODEL, 4 * D_MODEL);
    }
  }
}

// Round 14
// 308.134 us; speedup vs baseline: 1.2952x; 1.0351x over previous
//
#include <hip/hip_runtime.h>

// ---------------------------------------------------------------------------
// Transformer block on MI355X. fp32 I/O (per reference), bf16 MFMA internals,
// fp32 accumulation/residuals.
// R23: flash split=1 + in-epilogue normalization. With one block covering all
// 2048 keys, l is final at the epilogue -> flash writes NORMALIZED bf16 attn
// directly (lane-local: accO * KH_ISCALE/accL, same C/D row). Deletes Opart
// (16MB w + 16MB r -> 8MB w + 8MB r), lpart, and gemm_proj's fused-combine
// (proj = plain gemm_bt<2> now). Flash total work unchanged (16 tiles x 512
// blocks, 2/CU); XCD locality 4 heads = 1MB/XCD. attn scratch lives in d_out
// (dead until FC2 writes it) as in R10.
// R22/R17 kept: 2-phase dbuf 64^2 gemm_bt (kh/proj/FC2 -- FC2 plateau escape
// REFUTED x3: split-K disjoint+interleaved both FETCH 90MB, register-B
// uncoalesced 142us); gemm256 8-phase 256^2 w/ register-resident fragments
// (FC1); flash tr-read V subtiled lsK; XCD-chunk swizzle; kexp folded in kh.
// ws layout (56MB min, 72MB preferred):
//   [0,16M)  free  | big: fc1o [0,32M) after proj | small: wTk/wTf1/wTf2
//   [16,24M) kh    | small: fc1o [16,32M)
//   [24,32M) wTp (small path)
//   [32,48M) x1    [48,56M) hbuf
//   [56,64M) wT1 (big), [64,72M) wT2 (big)
// attn (bf16 8MB) lives in d_out, dead before FC2 writes d_out.
// ---------------------------------------------------------------------------

typedef __attribute__((ext_vector_type(8))) short s8v;  // 8 bf16 raw
typedef __attribute__((ext_vector_type(4))) short s4v;  // 4 bf16 raw
typedef __attribute__((ext_vector_type(4))) float f4v;  // mfma accumulator

#define D_MODEL 1024
#define SEQ 2048
#define BATCH 2
#define NH 16
#define DH 64
#define MROWS (BATCH * SEQ)

#define KH_SCALE 0.42466088f
#define KH_ISCALE 2.3548200f

__device__ __forceinline__ float b2f(unsigned short u) {
  union { unsigned int i; float f; } v; v.i = ((unsigned int)u) << 16; return v.f;
}
__device__ __forceinline__ unsigned short f2b(float f) {
  unsigned int i = __builtin_bit_cast(unsigned int, f);
  unsigned int r = (i + 0x7fffu + ((i >> 16) & 1u)) >> 16;  // RNE
  return (unsigned short)r;
}
// async global->LDS, 16B/lane; dest = wave-uniform base + lane*16 (m104/m108)
__device__ __forceinline__ void async16(const void* g, void* l) {
  __builtin_amdgcn_global_load_lds(
      (const __attribute__((address_space(1))) unsigned int*)g,
      (__attribute__((address_space(3))) unsigned int*)l, 16, 0, 0);
}
__device__ __forceinline__ unsigned short cvt_b(float f) { return f2b(f); }
__device__ __forceinline__ unsigned short cvt_b(unsigned short u) { return u; }

__device__ __forceinline__ float xp2(float x) {
#if __has_builtin(__builtin_amdgcn_exp2f)
  return __builtin_amdgcn_exp2f(x);
#else
  return exp2f(x);
#endif
}

// 4x f32 -> packed bf16 s4v via v_cvt_pk_bf16_f32 (RNE, 2 instructions).
__device__ __forceinline__ s4v cvt4(float a, float b, float c, float d) {
  unsigned int lo, hi;
  asm("v_cvt_pk_bf16_f32 %0, %1, %2" : "=v"(lo) : "v"(a), "v"(b));
  asm("v_cvt_pk_bf16_f32 %0, %1, %2" : "=v"(hi) : "v"(c), "v"(d));
  union { unsigned long long u; s4v v; } u;
  u.u = ((unsigned long long)hi << 32) | (unsigned long long)lo;
  return u.v;
}

#if __has_builtin(__builtin_amdgcn_mfma_f32_16x16x16_bf16)
__device__ __forceinline__ f4v mfma16(s4v a, s4v b, f4v c) {
  return __builtin_amdgcn_mfma_f32_16x16x16_bf16(a, b, c, 0, 0, 0);
}
#elif __has_builtin(__builtin_amdgcn_mfma_f32_16x16x16bf16_1k)
__device__ __forceinline__ f4v mfma16(s4v a, s4v b, f4v c) {
  return __builtin_amdgcn_mfma_f32_16x16x16bf16_1k(a, b, c, 0, 0, 0);
}
#else
__device__ __forceinline__ f4v mfma16(s4v a, s4v b, f4v c) {
  s8v aa = {a[0], a[1], a[2], a[3], 0, 0, 0, 0};
  s8v bb = {b[0], b[1], b[2], b[3], 0, 0, 0, 0};
  return __builtin_amdgcn_mfma_f32_16x16x32_bf16(aa, bb, c, 0, 0, 0);
}
#endif

// LDS transpose-read: supply the natural per-lane ds_read_b64 address
// (base + lane*8B); each 16-lane group's 128B region is delivered
// column-major: lane l gets column (l&15) of its 4x16 bf16 tile (m156/m162).
typedef __attribute__((address_space(3))) const unsigned short* lds_cp;
__device__ __forceinline__ s4v tr16(lds_cp p) {
  unsigned long long d;
  asm volatile("ds_read_b64_tr_b16 %0, %1" : "=v"(d) : "v"(p));
  return __builtin_bit_cast(s4v, d);
}

// XCD-chunked logical block id (T1); bijective only when nwg%8==0.
__device__ __forceinline__ int xcd_swz(int bidl, int nwg) {
  return (nwg & 7) ? bidl : ((bidl & 7) * (nwg >> 3) + (bidl >> 3));
}

// ---------------- LayerNorm: fp32 in -> bf16 out, one block per row ---------
__global__ __launch_bounds__(256) void ln_kernel(
    const float* __restrict__ x, const float* __restrict__ g,
    const float* __restrict__ bb, unsigned short* __restrict__ out) {
  int row = blockIdx.x;
  int t = threadIdx.x;
  const float* xr = x + (size_t)row * D_MODEL;
  float v[4];
  float s = 0.f, s2 = 0.f;
#pragma unroll
  for (int i = 0; i < 4; ++i) {
    float f = xr[t + 256 * i];
    v[i] = f; s += f; s2 += f * f;
  }
#pragma unroll
  for (int off = 1; off < 64; off <<= 1) {
    s += __shfl_xor(s, off, 64);
    s2 += __shfl_xor(s2, off, 64);
  }
  __shared__ float red[8];
  if ((t & 63) == 0) { red[t >> 6] = s; red[4 + (t >> 6)] = s2; }
  __syncthreads();
  s = red[0] + red[1] + red[2] + red[3];
  s2 = red[4] + red[5] + red[6] + red[7];
  float mu = s * (1.f / D_MODEL);
  float var = s2 * (1.f / D_MODEL) - mu * mu;
  float rstd = rsqrtf(var + 1e-5f);
#pragma unroll
  for (int i = 0; i < 4; ++i) {
    int c = t + 256 * i;
    float h = (v[i] - mu) * rstd * g[c] + bb[c];
    out[(size_t)row * D_MODEL + c] = f2b(h);
  }
}

// ---------------- batched 64x64 tile transpose -> bf16 ----------------------
template <typename T>
__global__ __launch_bounds__(256) void transpose_b(
    const T* __restrict__ src, unsigned short* __restrict__ dst,
    int srcStride, int dstStride, long long srcBatch, long long dstBatch) {
  __shared__ unsigned short tile[64][65];
  const T* s = src + (size_t)blockIdx.z * srcBatch;
  unsigned short* d = dst + (size_t)blockIdx.z * dstBatch;
  int n0 = blockIdx.x * 64, k0 = blockIdx.y * 64;
  for (int i = threadIdx.x; i < 4096; i += 256) {
    int k = i >> 6, n = i & 63;
    tile[k][n] = cvt_b(s[(size_t)(k0 + k) * srcStride + n0 + n]);
  }
  __syncthreads();
  for (int i = threadIdx.x; i < 4096; i += 256) {
    int n = i >> 6, k = i & 63;
    d[(size_t)(n0 + n) * dstStride + k0 + k] = tile[k][n];
  }
}

// ---------------- GEMM: C[M,N] = A[M,K] @ Bt[N,K]^T + bias (+res)(+relu) ----
// BMxBN tile, BK=64, 4 waves (2x2); 2-phase dbuf, counted vmcnt, raw barrier.
template <int RES, bool RELU, bool KH, int OUTF, int BM, int BN>
__global__ __launch_bounds__(256) void gemm_bt(
    const unsigned short* __restrict__ A, const unsigned short* __restrict__ Bt,
    const float* __restrict__ bias, const float* __restrict__ res,
    void* __restrict__ out, int M, int N, int K) {
  constexpr int MT = BM / 32;
  constexpr int NT = BN / 32;
  __shared__ __align__(16) unsigned short lsA[2][BM * 64];
  __shared__ __align__(16) unsigned short lsB[2][BN * 64];
  int tid = threadIdx.x;
  int lane = tid & 63, w = tid >> 6, quad = lane >> 4, l16 = lane & 15;
  int bidl = blockIdx.y * (int)gridDim.x + blockIdx.x;
  int swz = xcd_swz(bidl, (int)(gridDim.x * gridDim.y));
  int m0 = (swz / (int)gridDim.x) * BM, n0 = (swz % (int)gridDim.x) * BN;
  int wm = (w >> 1) * (BM / 2), wn = (w & 1) * (BN / 2);
  f4v acc[MT][NT] = {};

  auto stage = [&](int bsel, int ktE) {
#pragma unroll
    for (int i = 0; i < MT; ++i) {
      int cb = w * (BM * 2) + i * 64;
      int ci = cb + lane;
      int row = ci >> 3, c = ci & 7;
      int cs = c ^ (row & 7);
      async16(A + (size_t)(m0 + row) * K + ktE + cs * 8, &lsA[bsel][cb * 8]);
    }
#pragma unroll
    for (int i = 0; i < NT; ++i) {
      int cb = w * (BN * 2) + i * 64;
      int ci = cb + lane;
      int row = ci >> 3, c = ci & 7;
      int cs = c ^ (row & 7);
      async16(Bt + (size_t)(n0 + row) * K + ktE + cs * 8, &lsB[bsel][cb * 8]);
    }
  };

  stage(0, 0);
  int nK = K >> 6;
  for (int kt = 0; kt < nK; ++kt) {
    int b = kt & 1;
    if (kt + 1 < nK) {
      stage(b ^ 1, (kt + 1) << 6);
      if constexpr (MT + NT == 4)      asm volatile("s_waitcnt vmcnt(4)" ::: "memory");
      else if constexpr (MT + NT == 6) asm volatile("s_waitcnt vmcnt(6)" ::: "memory");
      else                             asm volatile("s_waitcnt vmcnt(8)" ::: "memory");
    } else {
      asm volatile("s_waitcnt vmcnt(0)" ::: "memory");
    }
    __builtin_amdgcn_sched_barrier(0);
    __builtin_amdgcn_s_barrier();
    __builtin_amdgcn_sched_barrier(0);
#pragma unroll
    for (int s = 0; s < 2; ++s) {
      s8v af[MT], bf[NT];
#pragma unroll
      for (int t = 0; t < MT; ++t) {
        int am = wm + t * 16 + l16;
        int ac = (s * 4 + quad) ^ (am & 7);
        af[t] = *(const s8v*)(&lsA[b][am * 64 + ac * 8]);
      }
#pragma unroll
      for (int t = 0; t < NT; ++t) {
        int bn = wn + t * 16 + l16;
        int bc = (s * 4 + quad) ^ (bn & 7);
        bf[t] = *(const s8v*)(&lsB[b][bn * 64 + bc * 8]);
      }
#pragma unroll
      for (int ti = 0; ti < MT; ++ti)
#pragma unroll
        for (int tj = 0; tj < NT; ++tj)
          acc[ti][tj] = __builtin_amdgcn_mfma_f32_16x16x32_bf16(
              af[ti], bf[tj], acc[ti][tj], 0, 0, 0);
    }
    asm volatile("s_waitcnt lgkmcnt(0)" ::: "memory");
    __builtin_amdgcn_sched_barrier(0);
    __builtin_amdgcn_s_barrier();
    __builtin_amdgcn_sched_barrier(0);
  }
#pragma unroll
  for (int tj = 0; tj < NT; ++tj) {
    int col = n0 + wn + tj * 16 + l16;
    float bv = bias[col];
#pragma unroll
    for (int ti = 0; ti < MT; ++ti) {
#pragma unroll
      for (int r = 0; r < 4; ++r) {
        int rowg = m0 + wm + ti * 16 + quad * 4 + r;
        float vv = acc[ti][tj][r] + bv;
        if (KH) vv *= KH_SCALE;
        if (RES == 2) vv += res[(size_t)rowg * N + col];
        if (RELU) vv = fmaxf(vv, 0.f);
        size_t oidx;
        if (KH) {
          int b2 = rowg >> 11, l = rowg & 2047, h = col >> 6, d = col & 63;
          oidx = (((size_t)(b2 * NH + h)) * SEQ + l) * DH + d;
        } else {
          oidx = (size_t)rowg * N + col;
        }
        if (OUTF == 0) ((unsigned short*)out)[oidx] = f2b(vv);
        else           ((float*)out)[oidx] = vv;
      }
    }
  }
}

// ---------------- 256x256 8-phase GEMM (T3+T4+T5), bf16 out + bias (+relu) --
// R17: fragments register-resident across reusing phases. af[MH] read at
// MH's first phase (ph1/ph2), bf[NH] at NH's first phase (ph1/ph3); ph4/ph8
// read nothing. 24 ds_read_b128 per K-tile (was 48).
__global__ __launch_bounds__(512, 2) void gemm256(
    const unsigned short* __restrict__ A, const unsigned short* __restrict__ Bt,
    const float* __restrict__ bias, unsigned short* __restrict__ out,
    bool relu, int M, int N, int K) {
  __shared__ __align__(16) unsigned short lsA[2][2][128 * 64];
  __shared__ __align__(16) unsigned short lsB[2][2][128 * 64];
  int tid = threadIdx.x;
  int lane = tid & 63, w = tid >> 6, quad = lane >> 4, l16 = lane & 15;
  int wr = w >> 2, wc = w & 3;
  int bidl = blockIdx.y * (int)gridDim.x + blockIdx.x;
  int swz = xcd_swz(bidl, (int)(gridDim.x * gridDim.y));
  int m0 = (swz / (int)gridDim.x) * 256, n0 = (swz % (int)gridDim.x) * 256;
  f4v acc[8][4] = {};
  s8v afh[2][4][2];  // held A fragments [MH][tm][s]
  s8v bfh[2][2][2];  // held B fragments [NH][tn][s]

  auto stageA = [&](int par, int h, int kt) {
#pragma unroll
    for (int i = 0; i < 2; ++i) {
      int cb = w * 128 + i * 64;
      int ci = cb + lane;
      int r = ci >> 3, c = ci & 7;
      int cs = c ^ (r & 7);
      int grow = ((r >> 6) << 7) + h * 64 + (r & 63);
      async16(A + (size_t)(m0 + grow) * K + kt * 64 + cs * 8,
              &lsA[par][h][cb * 8]);
    }
  };
  auto stageB = [&](int par, int h, int kt) {
#pragma unroll
    for (int i = 0; i < 2; ++i) {
      int cb = w * 128 + i * 64;
      int ci = cb + lane;
      int r = ci >> 3, c = ci & 7;
      int cs = c ^ (r & 7);
      int gn = ((r >> 5) << 6) + h * 32 + (r & 31);
      async16(Bt + (size_t)(n0 + gn) * K + kt * 64 + cs * 8,
              &lsB[par][h][cb * 8]);
    }
  };

#define PHASE(PAR, MH, NH, RA, RB, STAGE_STMT, VMN)                            \
  {                                                                            \
    if (RA) {                                                                  \
      _Pragma("unroll") for (int tm = 0; tm < 4; ++tm) {                       \
        int lr = wr * 64 + tm * 16 + l16;                                      \
        _Pragma("unroll") for (int s = 0; s < 2; ++s) {                        \
          int ac = (s * 4 + quad) ^ (lr & 7);                                  \
          afh[MH][tm][s] = *(const s8v*)(&lsA[PAR][MH][lr * 64 + ac * 8]);     \
        }                                                                      \
      }                                                                        \
    }                                                                          \
    if (RB) {                                                                  \
      _Pragma("unroll") for (int tn = 0; tn < 2; ++tn) {                       \
        int rb = wc * 32 + tn * 16 + l16;                                      \
        _Pragma("unroll") for (int s = 0; s < 2; ++s) {                        \
          int bc = (s * 4 + quad) ^ (rb & 7);                                  \
          bfh[NH][tn][s] = *(const s8v*)(&lsB[PAR][NH][rb * 64 + bc * 8]);     \
        }                                                                      \
      }                                                                        \
    }                                                                          \
    STAGE_STMT;                                                                \
    __builtin_amdgcn_sched_barrier(0);                                         \
    __builtin_amdgcn_s_barrier();                                              \
    __builtin_amdgcn_sched_barrier(0);                                         \
    __builtin_amdgcn_s_setprio(1);                                             \
    _Pragma("unroll") for (int s = 0; s < 2; ++s)                              \
      _Pragma("unroll") for (int tm = 0; tm < 4; ++tm)                         \
        _Pragma("unroll") for (int tn = 0; tn < 2; ++tn)                       \
          acc[MH * 4 + tm][NH * 2 + tn] =                                      \
              __builtin_amdgcn_mfma_f32_16x16x32_bf16(                         \
                  afh[MH][tm][s], bfh[NH][tn][s],                              \
                  acc[MH * 4 + tm][NH * 2 + tn], 0, 0, 0);                     \
    __builtin_amdgcn_s_setprio(0);                                             \
    __builtin_amdgcn_sched_barrier(0);                                         \
    if (VMN == 4) { asm volatile("s_waitcnt vmcnt(4)" ::: "memory"); }         \
    else if (VMN == 0) { asm volatile("s_waitcnt vmcnt(0)" ::: "memory"); }    \
    __builtin_amdgcn_sched_barrier(0);                                         \
    __builtin_amdgcn_s_barrier();                                              \
    __builtin_amdgcn_sched_barrier(0);                                         \
  }

  int nT = K >> 6;  // assumes nT even, >= 4
  stageA(0, 0, 0); stageB(0, 0, 0); stageA(0, 1, 0); stageB(0, 1, 0);
  stageB(1, 0, 1); stageA(1, 0, 1);
  asm volatile("s_waitcnt vmcnt(4)" ::: "memory");
  __builtin_amdgcn_sched_barrier(0);
  __builtin_amdgcn_s_barrier();
  __builtin_amdgcn_sched_barrier(0);

  for (int t = 0; t < nT; t += 2) {
    bool s2 = (t + 2) < nT, s3 = (t + 3) < nT;
    PHASE(0, 0, 0, 1, 1, { stageA(1, 1, t + 1); }, -1)                 // ph1
    PHASE(0, 1, 0, 1, 0, { stageB(1, 1, t + 1); }, -1)                 // ph2
    PHASE(0, 0, 1, 0, 1, { if (s2) stageB(0, 0, t + 2); }, -1)         // ph3
    PHASE(0, 1, 1, 0, 0, { if (s2) stageA(0, 0, t + 2); }, (s2 ? 4 : 0)) // ph4
    PHASE(1, 0, 0, 1, 1, { if (s2) stageA(0, 1, t + 2); }, -1)         // ph5
    PHASE(1, 1, 0, 1, 0, { if (s2) stageB(0, 1, t + 2); }, -1)         // ph6
    PHASE(1, 0, 1, 0, 1, { if (s3) stageB(1, 0, t + 3); }, -1)         // ph7
    PHASE(1, 1, 1, 0, 0, { if (s3) stageA(1, 0, t + 3); }, (s3 ? 4 : 0)) // ph8
  }
#undef PHASE

#pragma unroll
  for (int mi = 0; mi < 8; ++mi) {
    int mh = mi >> 2, tm = mi & 3;
#pragma unroll
    for (int nj = 0; nj < 4; ++nj) {
      int nh = nj >> 1, tn = nj & 1;
      int col = n0 + wc * 64 + nh * 32 + tn * 16 + l16;
      float bv = bias[col];
#pragma unroll
      for (int r = 0; r < 4; ++r) {
        int rowg = m0 + wr * 128 + mh * 64 + tm * 16 + quad * 4 + r;
        float vv = acc[mi][nj][r] + bv;
        if (relu) vv = fmaxf(vv, 0.f);
        out[(size_t)rowg * N + col] = f2b(vv);
      }
    }
  }
}

// ---------------- fused flash attention, split=1, normalized output ---------
// grid (bh=32, qb=16): linear id = qb*32+bh => id%8 = bh%8 -> all qb-blocks
// of a head share an XCD; per-XCD working set = 4 heads x 256KB = 1MB.
// One block covers all 2048 keys (16 staging tiles) -> l final at epilogue;
// normalize in fp32 and write bf16 attn directly (no Opart/lpart/combine).
// lsK subtiled [4 dblk][128 key][16 d], double-buffered; V via tr16.
__global__ __launch_bounds__(256) void flash_k(
    const unsigned short* __restrict__ kh, unsigned short* __restrict__ attn) {
  __shared__ __align__(16) unsigned short lsK[2][8192];  // 2x16KB subtiled
  int tid = threadIdx.x;
  int lane = tid & 63, w = tid >> 6, quad = lane >> 4, l16 = lane & 15;
  int bh = blockIdx.x, qb = blockIdx.y;
  const unsigned short* khB = kh + (size_t)bh * SEQ * DH;
  s8v aQ[2][2];
#pragma unroll
  for (int g = 0; g < 2; ++g) {
    int q = qb * 128 + w * 32 + g * 16 + l16;
#pragma unroll
    for (int s = 0; s < 2; ++s)
      aQ[g][s] = *(const s8v*)(khB + (size_t)q * DH + s * 32 + quad * 8);
  }
  const s8v vone8 = {(short)0x3F80, (short)0x3F80, (short)0x3F80, (short)0x3F80,
                     (short)0x3F80, (short)0x3F80, (short)0x3F80, (short)0x3F80};
  f4v accO[2][4] = {};
  f4v accL[2] = {};  // row q = quad*4+r (col-replicated), l-sums via MFMA

  auto stageK = [&](int bsel, int key0) {
#pragma unroll
    for (int i = 0; i < 4; ++i) {
      int ci = w * 256 + i * 64 + lane;
      async16(khB + (size_t)(key0 + ((ci >> 1) & 127)) * DH +
                  (ci >> 8) * 16 + (ci & 1) * 8,
              &lsK[bsel][(w * 256 + i * 64) * 8]);
    }
  };
  lds_cp ls0 = (lds_cp)&lsK[0][0];
  lds_cp trb = ls0 + quad * 64 + l16 * 4;  // elements

  stageK(0, 0);
  for (int kt8 = 0; kt8 < 16; ++kt8) {
    int b = kt8 & 1;
    if (kt8 + 1 < 16) {
      stageK(b ^ 1, (kt8 + 1) * 128);
      asm volatile("s_waitcnt vmcnt(4)" ::: "memory");
    } else {
      asm volatile("s_waitcnt vmcnt(0)" ::: "memory");
    }
    __builtin_amdgcn_sched_barrier(0);
    __builtin_amdgcn_s_barrier();
    __builtin_amdgcn_sched_barrier(0);
#pragma unroll
    for (int half = 0; half < 2; ++half) {
      // S^T = K @ Q^T over 64 keys (lane = key within sub-tile)
      f4v accST[2][4] = {};
#pragma unroll
      for (int s = 0; s < 2; ++s) {
#pragma unroll
        for (int tj = 0; tj < 4; ++tj) {
          s8v kf = *(const s8v*)(&lsK[b][(2 * s + (quad >> 1)) * 2048 +
                                         (half * 64 + tj * 16 + l16) * 16 +
                                         (quad & 1) * 8]);
#pragma unroll
          for (int g = 0; g < 2; ++g)
            accST[g][tj] = __builtin_amdgcn_mfma_f32_16x16x32_bf16(
                kf, aQ[g][s], accST[g][tj], 0, 0, 0);
        }
      }
      s4v pprev[2];
#pragma unroll
      for (int tj = 0; tj < 4; ++tj) {
        s4v vt[4];
#pragma unroll
        for (int db = 0; db < 4; ++db)
          vt[db] = tr16(trb + b * 8192 + db * 2048 + half * 1024 + tj * 256);
        s4v pf[2];
#pragma unroll
        for (int g = 0; g < 2; ++g) {
          float p0 = xp2(accST[g][tj][0]);
          float p1 = xp2(accST[g][tj][1]);
          float p2 = xp2(accST[g][tj][2]);
          float p3 = xp2(accST[g][tj][3]);
          pf[g] = cvt4(p0, p1, p2, p3);
        }
        if (tj & 1) {
#pragma unroll
          for (int g = 0; g < 2; ++g) {
            s8v pp = {pprev[g][0], pprev[g][1], pprev[g][2], pprev[g][3],
                      pf[g][0], pf[g][1], pf[g][2], pf[g][3]};
            accL[g] = __builtin_amdgcn_mfma_f32_16x16x32_bf16(
                pp, vone8, accL[g], 0, 0, 0);  // B=1: k-position irrelevant
          }
        } else {
#pragma unroll
          for (int g = 0; g < 2; ++g) pprev[g] = pf[g];
        }
        asm volatile("s_waitcnt lgkmcnt(0)" ::: "memory");  // tr reads landed
        __builtin_amdgcn_sched_barrier(0);
#pragma unroll
        for (int db = 0; db < 4; ++db)
#pragma unroll
          for (int g = 0; g < 2; ++g)
            accO[g][db] = mfma16(pf[g], vt[db], accO[g][db]);
      }
    }
    asm volatile("s_waitcnt lgkmcnt(0)" ::: "memory");
    __builtin_amdgcn_sched_barrier(0);
    __builtin_amdgcn_s_barrier();
    __builtin_amdgcn_sched_barrier(0);
  }
  // epilogue: l final (all 2048 keys) -> normalize in fp32, write bf16 attn.
  // accL row q = quad*4+r matches accO's row; value replicated across l16.
  int b = bh >> 4, h = bh & 15;
#pragma unroll
  for (int g = 0; g < 2; ++g) {
#pragma unroll
    for (int r = 0; r < 4; ++r) {
      float inv = KH_ISCALE / accL[g][r];
      int l = qb * 128 + w * 32 + g * 16 + quad * 4 + r;
#pragma unroll
      for (int db = 0; db < 4; ++db) {
        int d = db * 16 + l16;
        attn[((size_t)(b * SEQ + l)) * D_MODEL + h * DH + d] =
            f2b(accO[g][db][r] * inv);
      }
    }
  }
}

// ---------------------------------------------------------------------------
extern "C" void kernel_launch(void* const* d_in, const int* in_sizes, int n_in,
                              void* d_out, int out_size, void* d_ws, size_t ws_size,
                              hipStream_t stream) {
  (void)in_sizes; (void)n_in; (void)out_size;
  const float* x      = (const float*)d_in[0];
  const float* w_attn = (const float*)d_in[1];
  const float* b_attn = (const float*)d_in[2];
  const float* w_proj = (const float*)d_in[3];
  const float* b_proj = (const float*)d_in[4];
  const float* ln1_g  = (const float*)d_in[5];
  const float* ln1_b  = (const float*)d_in[6];
  const float* ln2_g  = (const float*)d_in[7];
  const float* ln2_b  = (const float*)d_in[8];
  const float* w_fc1  = (const float*)d_in[9];
  const float* b_fc1  = (const float*)d_in[10];
  const float* w_fc2  = (const float*)d_in[11];
  const float* b_fc2  = (const float*)d_in[12];

  char* ws = (char*)d_ws;
  unsigned short* kh    = (unsigned short*)(ws + (size_t)(16u << 20)); // [16,24)
  float*          x1    = (float*)(ws + (size_t)(32u << 20));          // [32,48)
  unsigned short* hbuf  = (unsigned short*)(ws + (size_t)(48u << 20)); // [48,56)
  unsigned short* attn  = (unsigned short*)d_out;  // scratch, dead pre-FC2
  float* outf = (float*)d_out;
  bool big_ws = ws_size >= ((size_t)72u << 20);

  unsigned short* wTk;
  unsigned short* wTp;
  unsigned short* wTf1;
  unsigned short* wTf2;
  unsigned short* fc1o;
  if (big_ws) {
    wTk  = (unsigned short*)(ws + (size_t)(56u << 20));
    wTp  = wTk;
    wTf1 = wTk;
    wTf2 = (unsigned short*)(ws + (size_t)(64u << 20));
    fc1o = (unsigned short*)ws;                            // [0,32): kh dead
  } else {
    wTk  = (unsigned short*)ws;                            // [0,8)
    wTp  = (unsigned short*)(ws + (size_t)(24u << 20));    // [24,32)
    wTf1 = (unsigned short*)ws;                            // [0,8)
    wTf2 = (unsigned short*)(ws + (size_t)(8u << 20));     // [8,16)
    fc1o = kh;                                             // [16,32): chunked 16MB
  }

  dim3 blk(256);
  // 1. h1 = LN1(x)
  hipLaunchKernelGGL(ln_kernel, dim3(MROWS), blk, 0, stream, x, ln1_g, ln1_b, hbuf);
  // 2. wTk = (w_attn[:, 1024:2048])^T
  hipLaunchKernelGGL(transpose_b<float>, dim3(16, 16, 1), blk, 0, stream,
                     w_attn + 1024, wTk, 3 * D_MODEL, D_MODEL, 0LL, 0LL);
  // 3. kh[b,h,l,d] = (h1 @ w_k + b_k) * KH_SCALE
  hipLaunchKernelGGL((gemm_bt<0, false, true, 0, 64, 64>), dim3(16, 64), blk, 0,
                     stream, hbuf, wTk, b_attn + 1024, nullptr, (void*)kh,
                     MROWS, D_MODEL, D_MODEL);
  // 4. flash split=1 -> normalized bf16 attn (in d_out scratch)
  hipLaunchKernelGGL(flash_k, dim3(32, SEQ / 128), blk, 0, stream, kh, attn);
  // 5. wTp = w_proj^T ; x1 = attn @ w_proj + b + x  (plain gemm_bt)
  hipLaunchKernelGGL(transpose_b<float>, dim3(16, 16, 1), blk, 0, stream,
                     w_proj, wTp, D_MODEL, D_MODEL, 0LL, 0LL);
  hipLaunchKernelGGL((gemm_bt<2, false, false, 1, 64, 64>), dim3(16, 64), blk, 0,
                     stream, attn, wTp, b_proj, x, (void*)x1,
                     MROWS, D_MODEL, D_MODEL);
  // 6. h2 = LN2(x1)
  hipLaunchKernelGGL(ln_kernel, dim3(MROWS), blk, 0, stream, x1, ln2_g, ln2_b, hbuf);
  // 7. wTf1 = w_fc1^T ; wTf2 = w_fc2^T
  hipLaunchKernelGGL(transpose_b<float>, dim3(64, 16, 1), blk, 0, stream,
                     w_fc1, wTf1, 4 * D_MODEL, D_MODEL, 0LL, 0LL);
  hipLaunchKernelGGL(transpose_b<float>, dim3(16, 64, 1), blk, 0, stream,
                     w_fc2, wTf2, D_MODEL, 4 * D_MODEL, 0LL, 0LL);
  // 8/9. FFN: FC1 8-phase 256^2 (256 blocks = 1/CU); FC2 BM=64 (1024 blocks)
  if (big_ws) {
    hipLaunchKernelGGL(gemm256, dim3(16, 16), dim3(512), 0, stream,
                       hbuf, wTf1, b_fc1, fc1o, true,
                       MROWS, 4 * D_MODEL, D_MODEL);
    hipLaunchKernelGGL((gemm_bt<2, false, false, 1, 64, 64>), dim3(16, 64), blk, 0,
                       stream, fc1o, wTf2, b_fc2, x1, (void*)outf,
                       MROWS, D_MODEL, 4 * D_MODEL);
  } else {
    for (int c = 0; c < 2; ++c) {
      const unsigned short* h2c = hbuf + (size_t)c * 2048 * D_MODEL;
      const float* x1c = x1 + (size_t)c * 2048 * D_MODEL;
      float* outc = outf + (size_t)c * 2048 * D_MODEL;
      hipLaunchKernelGGL((gemm_bt<0, true, false, 0, 128, 64>), dim3(64, 16), blk, 0,
                         stream, h2c, wTf1, b_fc1, nullptr, (void*)fc1o,
                         2048, 4 * D_MODEL, D_MODEL);
      hipLaunchKernelGGL((gemm_bt<2, false, false, 1, 64, 64>), dim3(16, 32), blk, 0,
                         stream, fc1o, wTf2, b_fc2, x1c, (void*)outc,
                         2048, D_MODEL, 4 * D_MODEL);
    }
  }
}